// Round 1
// baseline (878.106 us; speedup 1.0000x reference)
//
#include <hip/hip_runtime.h>

typedef __bf16 bf16x8 __attribute__((ext_vector_type(8)));
typedef float f32x4 __attribute__((ext_vector_type(4)));
typedef unsigned int u32x4 __attribute__((ext_vector_type(4)));
typedef unsigned short u16x4 __attribute__((ext_vector_type(4)));
typedef unsigned short u16x8 __attribute__((ext_vector_type(8)));

#define SEQ_T 4096
#define DMODEL 1024
#define HEADS 16
#define DKH 64
#define MTOK 16384  // N*T rows

__device__ __forceinline__ unsigned short f2bf(float f) {
  unsigned u = __builtin_bit_cast(unsigned int, f);
  u += 0x7FFFu + ((u >> 16) & 1u);
  return (unsigned short)(u >> 16);
}
__device__ __forceinline__ float bf2f(unsigned short h) {
  unsigned u = ((unsigned)h) << 16;
  return __builtin_bit_cast(float, u);
}

// ---------------- fp32 -> bf16 elementwise ----------------
__global__ void __launch_bounds__(256) k_cvt(const float* __restrict__ x,
                                             unsigned short* __restrict__ y,
                                             long long nelem) {
  long long i = ((long long)blockIdx.x * 256 + threadIdx.x) * 8;
  if (i >= nelem) return;
  u16x8 o;
#pragma unroll
  for (int j = 0; j < 8; ++j) o[j] = f2bf(x[i + j]);
  *(u16x8*)(y + i) = o;
}

// ---------------- W (K x N) fp32 -> Wt (N x K) bf16 ----------------
__global__ void __launch_bounds__(256) k_wtrans(const float* __restrict__ W,
                                                unsigned short* __restrict__ Wt,
                                                int K, int N) {
  __shared__ float tile[32][33];
  int bn = blockIdx.x * 32, bk = blockIdx.y * 32;
  int tx = threadIdx.x, ty = threadIdx.y;  // 32 x 8
#pragma unroll
  for (int j = 0; j < 32; j += 8)
    tile[ty + j][tx] = W[(size_t)(bk + ty + j) * N + bn + tx];
  __syncthreads();
#pragma unroll
  for (int j = 0; j < 32; j += 8)
    Wt[(size_t)(bn + ty + j) * K + bk + tx] = f2bf(tile[tx][ty + j]);
}

// ---------------- bf16 NT GEMM: C = A(MxK) * Bt(NxK)^T + bias ----------------
#define BM 128
#define BN 128
#define BK 32
#define LDT 40  // padded LDS stride (bf16 elems), 80B: 16B-aligned, ~2-way banks

template <int OBF>
__global__ void __launch_bounds__(256, 2)
k_gemm(const unsigned short* __restrict__ A, const unsigned short* __restrict__ Bt,
       const float* __restrict__ bias, void* __restrict__ C, int M, int N, int K) {
  __shared__ unsigned short As[BM * LDT];
  __shared__ unsigned short Bs[BN * LDT];
  const int tid = threadIdx.x;
  const int lane = tid & 63, wid = tid >> 6;
  const int wr = wid >> 1, wc = wid & 1;
  const int bm = blockIdx.y * BM, bn = blockIdx.x * BN;
  const int r0 = tid >> 2, kc0 = (tid & 3) * 8;
  const int r1 = r0 + 64;
  const int l15 = lane & 15, l4 = lane >> 4;

  f32x4 acc[4][4];
#pragma unroll
  for (int i = 0; i < 4; ++i)
#pragma unroll
    for (int j = 0; j < 4; ++j)
#pragma unroll
      for (int e = 0; e < 4; ++e) acc[i][j][e] = 0.f;

  const unsigned short* Ap0 = A + (size_t)(bm + r0) * K + kc0;
  const unsigned short* Ap1 = A + (size_t)(bm + r1) * K + kc0;
  const unsigned short* Bp0 = Bt + (size_t)(bn + r0) * K + kc0;
  const unsigned short* Bp1 = Bt + (size_t)(bn + r1) * K + kc0;

  for (int kt = 0; kt < K; kt += BK) {
    u32x4 a0 = *(const u32x4*)(Ap0 + kt);
    u32x4 a1 = *(const u32x4*)(Ap1 + kt);
    u32x4 b0 = *(const u32x4*)(Bp0 + kt);
    u32x4 b1 = *(const u32x4*)(Bp1 + kt);
    __syncthreads();  // previous tile fully consumed
    *(u32x4*)(As + r0 * LDT + kc0) = a0;
    *(u32x4*)(As + r1 * LDT + kc0) = a1;
    *(u32x4*)(Bs + r0 * LDT + kc0) = b0;
    *(u32x4*)(Bs + r1 * LDT + kc0) = b1;
    __syncthreads();  // tile ready
    bf16x8 af[4], bfr[4];
#pragma unroll
    for (int m = 0; m < 4; ++m)
      af[m] = *(const bf16x8*)(As + (wr * 64 + m * 16 + l15) * LDT + l4 * 8);
#pragma unroll
    for (int n = 0; n < 4; ++n)
      bfr[n] = *(const bf16x8*)(Bs + (wc * 64 + n * 16 + l15) * LDT + l4 * 8);
#pragma unroll
    for (int m = 0; m < 4; ++m)
#pragma unroll
      for (int n = 0; n < 4; ++n)
        acc[m][n] = __builtin_amdgcn_mfma_f32_16x16x32_bf16(af[m], bfr[n],
                                                            acc[m][n], 0, 0, 0);
  }

  const int crow = bm + wr * 64 + l4 * 4;
  const int ccol = bn + wc * 64 + l15;
#pragma unroll
  for (int m = 0; m < 4; ++m)
#pragma unroll
    for (int n = 0; n < 4; ++n) {
      int c = ccol + n * 16;
      float bj = bias[c];
#pragma unroll
      for (int e = 0; e < 4; ++e) {
        int r = crow + m * 16 + e;
        float v = acc[m][n][e] + bj;
        if (OBF)
          ((unsigned short*)C)[(size_t)r * N + c] = f2bf(v);
        else
          ((float*)C)[(size_t)r * N + c] = v;
      }
    }
}

// ---------------- alpha pooling: softmax(q . alpha_w) -> gq ----------------
__global__ void __launch_bounds__(256) k_alpha(const float* __restrict__ q,
                                               const int* __restrict__ mask,
                                               const float* __restrict__ alpha_w,
                                               float* __restrict__ gq) {
  __shared__ float sw[SEQ_T];
  __shared__ float red[4];
  __shared__ float part[16][64];
  const int tid = threadIdx.x, lane = tid & 63, wid = tid >> 6;
  const int n = blockIdx.x >> 4, h = blockIdx.x & 15;
  const int tsub = lane >> 4, dl = lane & 15;
  const float* qb = q + (size_t)n * SEQ_T * DMODEL + h * DKH;
  const int* mrow = mask + n * SEQ_T;
  f32x4 aw = *(const f32x4*)(alpha_w + dl * 4);

  for (int t0 = wid * 4; t0 < SEQ_T; t0 += 16) {
    int t = t0 + tsub;
    f32x4 qv = *(const f32x4*)(qb + (size_t)t * DMODEL + dl * 4);
    float p = qv[0] * aw[0] + qv[1] * aw[1] + qv[2] * aw[2] + qv[3] * aw[3];
    p += __shfl_xor(p, 1); p += __shfl_xor(p, 2);
    p += __shfl_xor(p, 4); p += __shfl_xor(p, 8);
    if (dl == 0) {
      float s = p * 0.125f;
      if (mrow[t] == 0) s = -3.0e38f;
      sw[t] = s;
    }
  }
  __syncthreads();
  float mx = -3.4e38f;
  for (int t = tid; t < SEQ_T; t += 256) mx = fmaxf(mx, sw[t]);
#pragma unroll
  for (int o = 1; o < 64; o <<= 1) mx = fmaxf(mx, __shfl_xor(mx, o));
  if (lane == 0) red[wid] = mx;
  __syncthreads();
  mx = fmaxf(fmaxf(red[0], red[1]), fmaxf(red[2], red[3]));
  __syncthreads();  // protect red[] before reuse
  float s = 0.f;
  for (int t = tid; t < SEQ_T; t += 256) {
    float e = __expf(sw[t] - mx);
    sw[t] = e;
    s += e;
  }
#pragma unroll
  for (int o = 1; o < 64; o <<= 1) s += __shfl_xor(s, o);
  if (lane == 0) red[wid] = s;
  __syncthreads();
  float inv = 1.f / (red[0] + red[1] + red[2] + red[3]);
  f32x4 acc = {0.f, 0.f, 0.f, 0.f};
  for (int t0 = wid * 4; t0 < SEQ_T; t0 += 16) {
    int t = t0 + tsub;
    float w = sw[t];
    f32x4 qv = *(const f32x4*)(qb + (size_t)t * DMODEL + dl * 4);
    acc[0] += w * qv[0]; acc[1] += w * qv[1];
    acc[2] += w * qv[2]; acc[3] += w * qv[3];
  }
  int g = wid * 4 + tsub;
#pragma unroll
  for (int e = 0; e < 4; ++e) part[g][dl * 4 + e] = acc[e];
  __syncthreads();
  if (tid < 64) {
    float v = 0.f;
#pragma unroll
    for (int gg = 0; gg < 16; ++gg) v += part[gg][tid];
    gq[blockIdx.x * 64 + tid] = v * inv;
  }
}

// ------- beta pooling: softmax((gq*k) . beta_w) ; gk = gq * sum(beta*k) -------
__global__ void __launch_bounds__(256) k_beta(const unsigned short* __restrict__ kk,
                                              const int* __restrict__ mask,
                                              const float* __restrict__ beta_w,
                                              const float* __restrict__ gq,
                                              float* __restrict__ gk) {
  __shared__ float sw[SEQ_T];
  __shared__ float red[4];
  __shared__ float part[16][64];
  const int tid = threadIdx.x, lane = tid & 63, wid = tid >> 6;
  const int n = blockIdx.x >> 4, h = blockIdx.x & 15;
  const int tsub = lane >> 4, dl = lane & 15;
  const unsigned short* kb = kk + (size_t)n * SEQ_T * DMODEL + h * DKH;
  const int* mrow = mask + n * SEQ_T;
  f32x4 g4 = *(const f32x4*)(gq + blockIdx.x * 64 + dl * 4);
  f32x4 bw = *(const f32x4*)(beta_w + dl * 4);
  f32x4 wv = {g4[0] * bw[0], g4[1] * bw[1], g4[2] * bw[2], g4[3] * bw[3]};

  for (int t0 = wid * 4; t0 < SEQ_T; t0 += 16) {
    int t = t0 + tsub;
    u16x4 kv = *(const u16x4*)(kb + (size_t)t * DMODEL + dl * 4);
    float p = bf2f(kv[0]) * wv[0] + bf2f(kv[1]) * wv[1] +
              bf2f(kv[2]) * wv[2] + bf2f(kv[3]) * wv[3];
    p += __shfl_xor(p, 1); p += __shfl_xor(p, 2);
    p += __shfl_xor(p, 4); p += __shfl_xor(p, 8);
    if (dl == 0) {
      float s = p * 0.125f;
      if (mrow[t] == 0) s = -3.0e38f;
      sw[t] = s;
    }
  }
  __syncthreads();
  float mx = -3.4e38f;
  for (int t = tid; t < SEQ_T; t += 256) mx = fmaxf(mx, sw[t]);
#pragma unroll
  for (int o = 1; o < 64; o <<= 1) mx = fmaxf(mx, __shfl_xor(mx, o));
  if (lane == 0) red[wid] = mx;
  __syncthreads();
  mx = fmaxf(fmaxf(red[0], red[1]), fmaxf(red[2], red[3]));
  __syncthreads();
  float s = 0.f;
  for (int t = tid; t < SEQ_T; t += 256) {
    float e = __expf(sw[t] - mx);
    sw[t] = e;
    s += e;
  }
#pragma unroll
  for (int o = 1; o < 64; o <<= 1) s += __shfl_xor(s, o);
  if (lane == 0) red[wid] = s;
  __syncthreads();
  float inv = 1.f / (red[0] + red[1] + red[2] + red[3]);
  f32x4 acc = {0.f, 0.f, 0.f, 0.f};
  for (int t0 = wid * 4; t0 < SEQ_T; t0 += 16) {
    int t = t0 + tsub;
    float w = sw[t];
    u16x4 kv = *(const u16x4*)(kb + (size_t)t * DMODEL + dl * 4);
    acc[0] += w * bf2f(kv[0]); acc[1] += w * bf2f(kv[1]);
    acc[2] += w * bf2f(kv[2]); acc[3] += w * bf2f(kv[3]);
  }
  int g = wid * 4 + tsub;
#pragma unroll
  for (int e = 0; e < 4; ++e) part[g][dl * 4 + e] = acc[e];
  __syncthreads();
  if (tid < 64) {
    float v = 0.f;
#pragma unroll
    for (int gg = 0; gg < 16; ++gg) v += part[gg][tid];
    gk[blockIdx.x * 64 + tid] = gq[blockIdx.x * 64 + tid] * v * inv;
  }
}

// -------- A = (gk*v) @ Wr + br + q, written bf16 (one wave per token-head) -----
__global__ void __launch_bounds__(256) k_abuild(const float* __restrict__ q,
                                                const unsigned short* __restrict__ v,
                                                const float* __restrict__ gk,
                                                const float* __restrict__ Wr,
                                                const float* __restrict__ br,
                                                unsigned short* __restrict__ A) {
  __shared__ float WrS[DKH * DKH];
  __shared__ float uS[4][DKH];
  const int tid = threadIdx.x, lane = tid & 63, wid = tid >> 6;
  for (int i = tid; i < DKH * DKH; i += 256) WrS[i] = Wr[i];
  size_t th = (size_t)blockIdx.x * 4 + wid;
  int h = (int)(th & 15);
  size_t nt = th >> 4;
  int n = (int)(nt >> 12);
  const size_t base = nt * DMODEL + (size_t)h * DKH;
  float gkd = gk[((size_t)n * HEADS + h) * DKH + lane];
  uS[wid][lane] = gkd * bf2f(v[base + lane]);
  __syncthreads();
  float acc = br[lane];
#pragma unroll
  for (int d = 0; d < DKH; d += 4) {
    f32x4 uv = *(const f32x4*)&uS[wid][d];
    acc += uv[0] * WrS[(d + 0) * DKH + lane];
    acc += uv[1] * WrS[(d + 1) * DKH + lane];
    acc += uv[2] * WrS[(d + 2) * DKH + lane];
    acc += uv[3] * WrS[(d + 3) * DKH + lane];
  }
  A[base + lane] = f2bf(acc + q[base + lane]);
}

extern "C" void kernel_launch(void* const* d_in, const int* in_sizes, int n_in,
                              void* d_out, int out_size, void* d_ws, size_t ws_size,
                              hipStream_t stream) {
  const float* x_k = (const float*)d_in[0];
  const float* x_v = (const float*)d_in[1];
  const float* x_q = (const float*)d_in[2];
  const int* mask = (const int*)d_in[3];
  const float* Wk = (const float*)d_in[4];
  const float* bk = (const float*)d_in[5];
  const float* Wv = (const float*)d_in[6];
  const float* bv = (const float*)d_in[7];
  const float* Wq = (const float*)d_in[8];
  const float* bq = (const float*)d_in[9];
  const float* alpha_w = (const float*)d_in[10];
  const float* beta_w = (const float*)d_in[11];
  const float* Wr = (const float*)d_in[12];
  const float* br = (const float*)d_in[13];
  const float* Wfc = (const float*)d_in[14];
  const float* bfc = (const float*)d_in[15];
  float* qf = (float*)d_out;  // fp32 q lives in d_out; dead before final GEMM

  char* ws = (char*)d_ws;
  const size_t SZ_XBF = (size_t)MTOK * DMODEL * 2;  // 32 MiB
  unsigned short* kbf = (unsigned short*)(ws);
  unsigned short* vbf = (unsigned short*)(ws + SZ_XBF);
  unsigned short* xst = (unsigned short*)(ws + 2 * SZ_XBF);  // x staging, later A
  unsigned short* WkT = (unsigned short*)(ws + 3 * SZ_XBF);
  unsigned short* WvT = WkT + (size_t)DMODEL * DMODEL;
  unsigned short* WqT = WvT + (size_t)DMODEL * DMODEL;
  unsigned short* WfT = WqT + (size_t)DMODEL * DMODEL;
  float* gq = (float*)(WfT + (size_t)DMODEL * DMODEL);
  float* gk = gq + 4096;

  dim3 tb(32, 8);
  dim3 tg(DMODEL / 32, DMODEL / 32);
  k_wtrans<<<tg, tb, 0, stream>>>(Wq, WqT, DMODEL, DMODEL);
  k_wtrans<<<tg, tb, 0, stream>>>(Wk, WkT, DMODEL, DMODEL);
  k_wtrans<<<tg, tb, 0, stream>>>(Wv, WvT, DMODEL, DMODEL);
  k_wtrans<<<tg, tb, 0, stream>>>(Wfc, WfT, DMODEL, DMODEL);

  long long nx = (long long)MTOK * DMODEL;
  int cvtg = (int)(nx / 8 / 256);
  dim3 ggrid(DMODEL / BN, MTOK / BM);

  k_cvt<<<cvtg, 256, 0, stream>>>(x_q, xst, nx);
  k_gemm<0><<<ggrid, 256, 0, stream>>>(xst, WqT, bq, (void*)qf, MTOK, DMODEL, DMODEL);
  k_cvt<<<cvtg, 256, 0, stream>>>(x_k, xst, nx);
  k_gemm<1><<<ggrid, 256, 0, stream>>>(xst, WkT, bk, (void*)kbf, MTOK, DMODEL, DMODEL);
  k_cvt<<<cvtg, 256, 0, stream>>>(x_v, xst, nx);
  k_gemm<1><<<ggrid, 256, 0, stream>>>(xst, WvT, bv, (void*)vbf, MTOK, DMODEL, DMODEL);

  k_alpha<<<64, 256, 0, stream>>>(qf, mask, alpha_w, gq);
  k_beta<<<64, 256, 0, stream>>>(kbf, mask, beta_w, gq, gk);
  k_abuild<<<(MTOK * HEADS) / 4, 256, 0, stream>>>(qf, vbf, gk, Wr, br, xst);
  k_gemm<0><<<ggrid, 256, 0, stream>>>(xst, WfT, bfc, d_out, MTOK, DMODEL, DMODEL);
}

// Round 2
// 458.067 us; speedup vs baseline: 1.9170x; 1.9170x over previous
//
#include <hip/hip_runtime.h>

typedef __bf16 bf16x8 __attribute__((ext_vector_type(8)));
typedef float f32x4 __attribute__((ext_vector_type(4)));
typedef unsigned int u32x4 __attribute__((ext_vector_type(4)));
typedef unsigned short u16x4 __attribute__((ext_vector_type(4)));
typedef unsigned short u16x8 __attribute__((ext_vector_type(8)));

#define SEQ_T 4096
#define DMODEL 1024
#define HEADS 16
#define DKH 64
#define MTOK 16384  // N*T rows

#define AS1 __attribute__((address_space(1)))
#define AS3 __attribute__((address_space(3)))

__device__ __forceinline__ unsigned short f2bf(float f) {
  unsigned u = __builtin_bit_cast(unsigned int, f);
  u += 0x7FFFu + ((u >> 16) & 1u);
  return (unsigned short)(u >> 16);
}
__device__ __forceinline__ float bf2f(unsigned short h) {
  unsigned u = ((unsigned)h) << 16;
  return __builtin_bit_cast(float, u);
}
__device__ __forceinline__ void gload16(const unsigned short* g, unsigned short* l) {
  __builtin_amdgcn_global_load_lds((const AS1 unsigned int*)(g),
                                   (AS3 unsigned int*)(l), 16, 0, 0);
}

// ---------------- fp32 -> bf16 elementwise ----------------
__global__ void __launch_bounds__(256) k_cvt(const float* __restrict__ x,
                                             unsigned short* __restrict__ y,
                                             long long nelem) {
  long long i = ((long long)blockIdx.x * 256 + threadIdx.x) * 8;
  if (i >= nelem) return;
  u16x8 o;
#pragma unroll
  for (int j = 0; j < 8; ++j) o[j] = f2bf(x[i + j]);
  *(u16x8*)(y + i) = o;
}

// ---------------- W (K x N) fp32 -> Wt (N x K) bf16 ----------------
__global__ void __launch_bounds__(256) k_wtrans(const float* __restrict__ W,
                                                unsigned short* __restrict__ Wt,
                                                int K, int N) {
  __shared__ float tile[32][33];
  int bn = blockIdx.x * 32, bk = blockIdx.y * 32;
  int tx = threadIdx.x, ty = threadIdx.y;  // 32 x 8
#pragma unroll
  for (int j = 0; j < 32; j += 8)
    tile[ty + j][tx] = W[(size_t)(bk + ty + j) * N + bn + tx];
  __syncthreads();
#pragma unroll
  for (int j = 0; j < 32; j += 8)
    Wt[(size_t)(bn + ty + j) * K + bk + tx] = f2bf(tile[tx][ty + j]);
}

// ------- bf16 NT GEMM (m97 structure): C = A(MxK) * Bt(NxK)^T + bias -------
#define BM 128
#define BN 128
#define BK 32

template <int OBF>
__global__ void __launch_bounds__(256, 2)
k_gemm(const unsigned short* __restrict__ A, const unsigned short* __restrict__ Bt,
       const float* __restrict__ bias, void* __restrict__ C, int M, int N, int K) {
  __shared__ unsigned short As[BM * BK];  // linear, gload_lds dest
  __shared__ unsigned short Bs[BN * BK];
  const int tid = threadIdx.x;
  const int lane = tid & 63, wid = tid >> 6;
  const int wr = wid >> 1, wc = wid & 1;
  const int bm = blockIdx.y * BM, bn = blockIdx.x * BN;
  const int l15 = lane & 15, l4 = lane >> 4;

  f32x4 acc[4][4];
#pragma unroll
  for (int i = 0; i < 4; ++i)
#pragma unroll
    for (int j = 0; j < 4; ++j)
#pragma unroll
      for (int e = 0; e < 4; ++e) acc[i][j][e] = 0.f;

  // staging: wave wid owns rows [wid*32, wid*32+32) of As and Bs.
  // per instruction: 16 rows x 64B, lane l -> row (l>>2), 16B chunk (l&3).
  const int srow = wid * 32 + (lane >> 2);
  const int scol = (lane & 3) * 8;
  const unsigned short* Ag = A + (size_t)(bm + srow) * K + scol;
  const unsigned short* Bg = Bt + (size_t)(bn + srow) * K + scol;
  unsigned short* Al = As + wid * 32 * BK;  // wave-uniform LDS base
  unsigned short* Bl = Bs + wid * 32 * BK;

  for (int kt = 0; kt < K; kt += BK) {
    __syncthreads();  // previous tile fully consumed
    gload16(Ag + kt, Al);
    gload16(Ag + kt + 16 * K, Al + 16 * BK);
    gload16(Bg + kt, Bl);
    gload16(Bg + kt + 16 * K, Bl + 16 * BK);
    __syncthreads();  // vmcnt drained -> tile visible
    bf16x8 af[4], bfr[4];
#pragma unroll
    for (int m = 0; m < 4; ++m)
      af[m] = *(const bf16x8*)(As + (wr * 64 + m * 16 + l15) * BK + l4 * 8);
#pragma unroll
    for (int n = 0; n < 4; ++n)
      bfr[n] = *(const bf16x8*)(Bs + (wc * 64 + n * 16 + l15) * BK + l4 * 8);
#pragma unroll
    for (int m = 0; m < 4; ++m)
#pragma unroll
      for (int n = 0; n < 4; ++n)
        acc[m][n] = __builtin_amdgcn_mfma_f32_16x16x32_bf16(af[m], bfr[n],
                                                            acc[m][n], 0, 0, 0);
  }

  const int crow = bm + wr * 64 + l4 * 4;
  const int ccol = bn + wc * 64 + l15;
#pragma unroll
  for (int m = 0; m < 4; ++m)
#pragma unroll
    for (int n = 0; n < 4; ++n) {
      int c = ccol + n * 16;
      float bj = bias[c];
#pragma unroll
      for (int e = 0; e < 4; ++e) {
        int r = crow + m * 16 + e;
        float v = acc[m][n][e] + bj;
        if (OBF)
          ((unsigned short*)C)[(size_t)r * N + c] = f2bf(v);
        else
          ((float*)C)[(size_t)r * N + c] = v;
      }
    }
}

// ---- alpha scores: s[nh][t] = scale * dot(q[n,t,h,:], alpha_w), masked ----
// grid 4096 blocks; each wave handles one token row (all 16 heads at once)
__global__ void __launch_bounds__(256) k_score_a(const float* __restrict__ q,
                                                 const int* __restrict__ mask,
                                                 const float* __restrict__ aw,
                                                 float* __restrict__ s) {
  const int tid = threadIdx.x, lane = tid & 63, wid = tid >> 6;
  size_t nt = (size_t)blockIdx.x * 4 + wid;
  int n = (int)(nt >> 12), t = (int)(nt & 4095);
  int h = lane >> 2, dq = (lane & 3) * 16;
  const float* qr = q + nt * DMODEL + h * DKH + dq;
  float p = 0.f;
#pragma unroll
  for (int j = 0; j < 16; j += 4) {
    f32x4 qv = *(const f32x4*)(qr + j);
    f32x4 av = *(const f32x4*)(aw + dq + j);
    p += qv[0] * av[0] + qv[1] * av[1] + qv[2] * av[2] + qv[3] * av[3];
  }
  p += __shfl_xor(p, 1);
  p += __shfl_xor(p, 2);
  if ((lane & 3) == 0) {
    float sc = p * 0.125f;
    if (mask[n * SEQ_T + t] == 0) sc = -3.0e38f;
    s[((size_t)n * HEADS + h) * SEQ_T + t] = sc;
  }
}

// ---- beta scores: s[nh][t] = scale * dot(k[n,t,h,:], gq[nh,:]*beta_w) ----
__global__ void __launch_bounds__(256) k_score_b(const unsigned short* __restrict__ kk,
                                                 const int* __restrict__ mask,
                                                 const float* __restrict__ bw,
                                                 const float* __restrict__ gq,
                                                 float* __restrict__ s) {
  const int tid = threadIdx.x, lane = tid & 63, wid = tid >> 6;
  size_t nt = (size_t)blockIdx.x * 4 + wid;
  int n = (int)(nt >> 12), t = (int)(nt & 4095);
  int h = lane >> 2, dq = (lane & 3) * 16;
  const unsigned short* kr = kk + nt * DMODEL + h * DKH + dq;
  const float* gr = gq + ((size_t)n * HEADS + h) * DKH + dq;
  float p = 0.f;
  u16x8 k0 = *(const u16x8*)(kr);
  u16x8 k1 = *(const u16x8*)(kr + 8);
#pragma unroll
  for (int j = 0; j < 8; ++j) {
    p += bf2f(k0[j]) * gr[j] * bw[dq + j];
    p += bf2f(k1[j]) * gr[8 + j] * bw[dq + 8 + j];
  }
  p += __shfl_xor(p, 1);
  p += __shfl_xor(p, 2);
  if ((lane & 3) == 0) {
    float sc = p * 0.125f;
    if (mask[n * SEQ_T + t] == 0) sc = -3.0e38f;
    s[((size_t)n * HEADS + h) * SEQ_T + t] = sc;
  }
}

// ---- per-(n,h) softmax stats: max and 1/sum(exp) over T ----
__global__ void __launch_bounds__(256) k_softmax(const float* __restrict__ s,
                                                 float* __restrict__ mxo,
                                                 float* __restrict__ invo) {
  __shared__ float red[4];
  const int tid = threadIdx.x, lane = tid & 63, wid = tid >> 6;
  const float* sb = s + (size_t)blockIdx.x * SEQ_T;
  float m = -3.4e38f;
  for (int t = tid; t < SEQ_T; t += 256) m = fmaxf(m, sb[t]);
#pragma unroll
  for (int o = 1; o < 64; o <<= 1) m = fmaxf(m, __shfl_xor(m, o));
  if (lane == 0) red[wid] = m;
  __syncthreads();
  m = fmaxf(fmaxf(red[0], red[1]), fmaxf(red[2], red[3]));
  __syncthreads();
  float sum = 0.f;
  for (int t = tid; t < SEQ_T; t += 256) sum += __expf(sb[t] - m);
#pragma unroll
  for (int o = 1; o < 64; o <<= 1) sum += __shfl_xor(sum, o);
  if (lane == 0) red[wid] = sum;
  __syncthreads();
  if (tid == 0) {
    mxo[blockIdx.x] = m;
    invo[blockIdx.x] = 1.f / (red[0] + red[1] + red[2] + red[3]);
  }
}

// ---- chunked weighted sum: pbuf[nh,chunk,:] = sum_t w[t]*X[n,t,h,:] ----
// grid 64*16 blocks (nh, 256-token chunk)
template <int BF>
__global__ void __launch_bounds__(256) k_wsum(const void* __restrict__ X,
                                              const float* __restrict__ s,
                                              const float* __restrict__ mxv,
                                              const float* __restrict__ invv,
                                              float* __restrict__ pbuf) {
  __shared__ float part[16][64];
  const int nh = blockIdx.x >> 4, chunk = blockIdx.x & 15;
  const int n = nh >> 4, h = nh & 15;
  const int tid = threadIdx.x, lane = tid & 63, wid = tid >> 6;
  const int tsub = lane >> 4, dl = lane & 15;
  const float mx = mxv[nh], inv = invv[nh];
  const float* sb = s + (size_t)nh * SEQ_T + chunk * 256;
  const size_t base = ((size_t)n * SEQ_T + chunk * 256) * DMODEL + h * DKH + dl * 4;
  f32x4 acc = {0.f, 0.f, 0.f, 0.f};
  for (int t = wid * 4 + tsub; t < 256; t += 16) {
    float w = __expf(sb[t] - mx) * inv;
    if (BF) {
      u16x4 xv = *(const u16x4*)((const unsigned short*)X + base + (size_t)t * DMODEL);
      acc[0] += w * bf2f(xv[0]); acc[1] += w * bf2f(xv[1]);
      acc[2] += w * bf2f(xv[2]); acc[3] += w * bf2f(xv[3]);
    } else {
      f32x4 xv = *(const f32x4*)((const float*)X + base + (size_t)t * DMODEL);
      acc[0] += w * xv[0]; acc[1] += w * xv[1];
      acc[2] += w * xv[2]; acc[3] += w * xv[3];
    }
  }
  int g = wid * 4 + tsub;
#pragma unroll
  for (int e = 0; e < 4; ++e) part[g][dl * 4 + e] = acc[e];
  __syncthreads();
  if (tid < 64) {
    float v = 0.f;
#pragma unroll
    for (int gg = 0; gg < 16; ++gg) v += part[gg][tid];
    pbuf[(size_t)blockIdx.x * 64 + tid] = v;
  }
}

// ---- final chunk reduce; MUL=1 additionally multiplies by gq (beta path) ----
template <int MUL>
__global__ void __launch_bounds__(64) k_fin(const float* __restrict__ pbuf,
                                            const float* __restrict__ gq,
                                            float* __restrict__ out) {
  const int nh = blockIdx.x, d = threadIdx.x;
  float v = 0.f;
#pragma unroll
  for (int c = 0; c < 16; ++c) v += pbuf[((size_t)nh * 16 + c) * 64 + d];
  if (MUL) v *= gq[(size_t)nh * 64 + d];
  out[(size_t)nh * 64 + d] = v;
}

// -------- A = (gk*v) @ Wr + br + q, written bf16 (one wave per token-head) -----
__global__ void __launch_bounds__(256) k_abuild(const float* __restrict__ q,
                                                const unsigned short* __restrict__ v,
                                                const float* __restrict__ gk,
                                                const float* __restrict__ Wr,
                                                const float* __restrict__ br,
                                                unsigned short* __restrict__ A) {
  __shared__ float WrS[DKH * DKH];
  __shared__ float uS[4][DKH];
  const int tid = threadIdx.x, lane = tid & 63, wid = tid >> 6;
  for (int i = tid; i < DKH * DKH; i += 256) WrS[i] = Wr[i];
  size_t th = (size_t)blockIdx.x * 4 + wid;
  int h = (int)(th & 15);
  size_t nt = th >> 4;
  int n = (int)(nt >> 12);
  const size_t base = nt * DMODEL + (size_t)h * DKH;
  float gkd = gk[((size_t)n * HEADS + h) * DKH + lane];
  uS[wid][lane] = gkd * bf2f(v[base + lane]);
  __syncthreads();
  float acc = br[lane];
#pragma unroll
  for (int d = 0; d < DKH; d += 4) {
    f32x4 uv = *(const f32x4*)&uS[wid][d];
    acc += uv[0] * WrS[(d + 0) * DKH + lane];
    acc += uv[1] * WrS[(d + 1) * DKH + lane];
    acc += uv[2] * WrS[(d + 2) * DKH + lane];
    acc += uv[3] * WrS[(d + 3) * DKH + lane];
  }
  A[base + lane] = f2bf(acc + q[base + lane]);
}

extern "C" void kernel_launch(void* const* d_in, const int* in_sizes, int n_in,
                              void* d_out, int out_size, void* d_ws, size_t ws_size,
                              hipStream_t stream) {
  const float* x_k = (const float*)d_in[0];
  const float* x_v = (const float*)d_in[1];
  const float* x_q = (const float*)d_in[2];
  const int* mask = (const int*)d_in[3];
  const float* Wk = (const float*)d_in[4];
  const float* bk = (const float*)d_in[5];
  const float* Wv = (const float*)d_in[6];
  const float* bv = (const float*)d_in[7];
  const float* Wq = (const float*)d_in[8];
  const float* bq = (const float*)d_in[9];
  const float* alpha_w = (const float*)d_in[10];
  const float* beta_w = (const float*)d_in[11];
  const float* Wr = (const float*)d_in[12];
  const float* br = (const float*)d_in[13];
  const float* Wfc = (const float*)d_in[14];
  const float* bfc = (const float*)d_in[15];
  float* qf = (float*)d_out;  // fp32 q lives in d_out; dead before final GEMM

  char* ws = (char*)d_ws;
  const size_t SZ_XBF = (size_t)MTOK * DMODEL * 2;  // 32 MiB
  unsigned short* kbf = (unsigned short*)(ws);
  unsigned short* vbf = (unsigned short*)(ws + SZ_XBF);
  unsigned short* xst = (unsigned short*)(ws + 2 * SZ_XBF);  // x staging, later A
  unsigned short* WkT = (unsigned short*)(ws + 3 * SZ_XBF);
  unsigned short* WvT = WkT + (size_t)DMODEL * DMODEL;
  unsigned short* WqT = WvT + (size_t)DMODEL * DMODEL;
  unsigned short* WfT = WqT + (size_t)DMODEL * DMODEL;
  float* gq = (float*)(WfT + (size_t)DMODEL * DMODEL);
  float* gk = gq + 4096;
  // pooling scratch overlaid on xst (dead between V-proj GEMM and abuild)
  float* sbuf = (float*)xst;                    // 64*4096 fp32 = 1 MiB
  float* pbuf = sbuf + (size_t)64 * SEQ_T;      // 1024*64 fp32 = 256 KiB
  float* smx = pbuf + 1024 * 64;                // 64
  float* sinv = smx + 64;                       // 64

  dim3 tb(32, 8);
  dim3 tg(DMODEL / 32, DMODEL / 32);
  k_wtrans<<<tg, tb, 0, stream>>>(Wq, WqT, DMODEL, DMODEL);
  k_wtrans<<<tg, tb, 0, stream>>>(Wk, WkT, DMODEL, DMODEL);
  k_wtrans<<<tg, tb, 0, stream>>>(Wv, WvT, DMODEL, DMODEL);
  k_wtrans<<<tg, tb, 0, stream>>>(Wfc, WfT, DMODEL, DMODEL);

  long long nx = (long long)MTOK * DMODEL;
  int cvtg = (int)(nx / 8 / 256);
  dim3 ggrid(DMODEL / BN, MTOK / BM);

  k_cvt<<<cvtg, 256, 0, stream>>>(x_q, xst, nx);
  k_gemm<0><<<ggrid, 256, 0, stream>>>(xst, WqT, bq, (void*)qf, MTOK, DMODEL, DMODEL);
  k_cvt<<<cvtg, 256, 0, stream>>>(x_k, xst, nx);
  k_gemm<1><<<ggrid, 256, 0, stream>>>(xst, WkT, bk, (void*)kbf, MTOK, DMODEL, DMODEL);
  k_cvt<<<cvtg, 256, 0, stream>>>(x_v, xst, nx);
  k_gemm<1><<<ggrid, 256, 0, stream>>>(xst, WvT, bv, (void*)vbf, MTOK, DMODEL, DMODEL);

  // ---- alpha pooling ----
  k_score_a<<<MTOK / 4, 256, 0, stream>>>(qf, mask, alpha_w, sbuf);
  k_softmax<<<64, 256, 0, stream>>>(sbuf, smx, sinv);
  k_wsum<0><<<1024, 256, 0, stream>>>((const void*)qf, sbuf, smx, sinv, pbuf);
  k_fin<0><<<64, 64, 0, stream>>>(pbuf, nullptr, gq);
  // ---- beta pooling ----
  k_score_b<<<MTOK / 4, 256, 0, stream>>>(kbf, mask, beta_w, gq, sbuf);
  k_softmax<<<64, 256, 0, stream>>>(sbuf, smx, sinv);
  k_wsum<1><<<1024, 256, 0, stream>>>((const void*)kbf, sbuf, smx, sinv, pbuf);
  k_fin<1><<<64, 64, 0, stream>>>(pbuf, gq, gk);

  k_abuild<<<(MTOK * HEADS) / 4, 256, 0, stream>>>(qf, vbf, gk, Wr, br, xst);
  k_gemm<0><<<ggrid, 256, 0, stream>>>(xst, WfT, bfc, d_out, MTOK, DMODEL, DMODEL);
}

// Round 3
// 328.371 us; speedup vs baseline: 2.6741x; 1.3950x over previous
//
#include <hip/hip_runtime.h>

typedef __bf16 bf16x8 __attribute__((ext_vector_type(8)));
typedef float f32x4 __attribute__((ext_vector_type(4)));
typedef unsigned int u32x4 __attribute__((ext_vector_type(4)));
typedef unsigned short u16x4 __attribute__((ext_vector_type(4)));
typedef unsigned short u16x8 __attribute__((ext_vector_type(8)));

#define SEQ_T 4096
#define DMODEL 1024
#define HEADS 16
#define DKH 64
#define MTOK 16384  // N*T rows

#define AS1 __attribute__((address_space(1)))
#define AS3 __attribute__((address_space(3)))

__device__ __forceinline__ unsigned short f2bf(float f) {
  unsigned u = __builtin_bit_cast(unsigned int, f);
  u += 0x7FFFu + ((u >> 16) & 1u);
  return (unsigned short)(u >> 16);
}
__device__ __forceinline__ float bf2f(unsigned short h) {
  unsigned u = ((unsigned)h) << 16;
  return __builtin_bit_cast(float, u);
}
__device__ __forceinline__ void gload16(const unsigned short* g, unsigned short* l) {
  __builtin_amdgcn_global_load_lds((const AS1 unsigned int*)(g),
                                   (AS3 unsigned int*)(l), 16, 0, 0);
}

// ---------------- fp32 -> bf16 elementwise ----------------
__global__ void __launch_bounds__(256) k_cvt(const float* __restrict__ x,
                                             unsigned short* __restrict__ y,
                                             long long nelem) {
  long long i = ((long long)blockIdx.x * 256 + threadIdx.x) * 8;
  if (i >= nelem) return;
  u16x8 o;
#pragma unroll
  for (int j = 0; j < 8; ++j) o[j] = f2bf(x[i + j]);
  *(u16x8*)(y + i) = o;
}

// ---------------- W (K x N) fp32 -> Wt (N x K) bf16 ----------------
__global__ void __launch_bounds__(256) k_wtrans(const float* __restrict__ W,
                                                unsigned short* __restrict__ Wt,
                                                int K, int N) {
  __shared__ float tile[32][33];
  int bn = blockIdx.x * 32, bk = blockIdx.y * 32;
  int tx = threadIdx.x, ty = threadIdx.y;  // 32 x 8
#pragma unroll
  for (int j = 0; j < 32; j += 8)
    tile[ty + j][tx] = W[(size_t)(bk + ty + j) * N + bn + tx];
  __syncthreads();
#pragma unroll
  for (int j = 0; j < 32; j += 8)
    Wt[(size_t)(bn + ty + j) * K + bk + tx] = f2bf(tile[tx][ty + j]);
}

// ------- bf16 NT GEMM (m97 structure): C = A(MxK) * Bt(NxK)^T + bias -------
// SCORE=1: also emit alpha scores (weights swt[dd]);  SCORE=2: beta scores
// (weights swt[nh][dd]).  Each block's 128 cols == heads {2*bx, 2*bx+1}.
#define BM 128
#define BN 128
#define BK 32

template <int OBF, int SCORE>
__global__ void __launch_bounds__(256, 2)
k_gemm(const unsigned short* __restrict__ A, const unsigned short* __restrict__ Bt,
       const float* __restrict__ bias, void* __restrict__ C,
       const int* __restrict__ mask, const float* __restrict__ swt,
       float* __restrict__ sbuf, int M, int N, int K) {
  __shared__ unsigned short As[BM * BK];  // linear, gload_lds dest
  __shared__ unsigned short Bs[BN * BK];
  const int tid = threadIdx.x;
  const int lane = tid & 63, wid = tid >> 6;
  const int wr = wid >> 1, wc = wid & 1;
  const int bnb = blockIdx.x;
  const int bm = blockIdx.y * BM, bn = bnb * BN;
  const int l15 = lane & 15, l4 = lane >> 4;

  f32x4 acc[4][4];
#pragma unroll
  for (int i = 0; i < 4; ++i)
#pragma unroll
    for (int j = 0; j < 4; ++j)
#pragma unroll
      for (int e = 0; e < 4; ++e) acc[i][j][e] = 0.f;

  const int srow = wid * 32 + (lane >> 2);
  const int scol = (lane & 3) * 8;
  const unsigned short* Ag = A + (size_t)(bm + srow) * K + scol;
  const unsigned short* Bg = Bt + (size_t)(bn + srow) * K + scol;
  unsigned short* Al = As + wid * 32 * BK;  // wave-uniform LDS base
  unsigned short* Bl = Bs + wid * 32 * BK;

  for (int kt = 0; kt < K; kt += BK) {
    __syncthreads();
    gload16(Ag + kt, Al);
    gload16(Ag + kt + 16 * K, Al + 16 * BK);
    gload16(Bg + kt, Bl);
    gload16(Bg + kt + 16 * K, Bl + 16 * BK);
    __syncthreads();
    bf16x8 af[4], bfr[4];
#pragma unroll
    for (int m = 0; m < 4; ++m)
      af[m] = *(const bf16x8*)(As + (wr * 64 + m * 16 + l15) * BK + l4 * 8);
#pragma unroll
    for (int n = 0; n < 4; ++n)
      bfr[n] = *(const bf16x8*)(Bs + (wc * 64 + n * 16 + l15) * BK + l4 * 8);
#pragma unroll
    for (int m = 0; m < 4; ++m)
#pragma unroll
      for (int n = 0; n < 4; ++n)
        acc[m][n] = __builtin_amdgcn_mfma_f32_16x16x32_bf16(af[m], bfr[n],
                                                            acc[m][n], 0, 0, 0);
  }

  const int crow = bm + wr * 64 + l4 * 4;
  const int ccol = bn + wc * 64 + l15;

  float pacc[4][4];
  const float* wrow = nullptr;
  if (SCORE == 1) wrow = swt;
  if (SCORE == 2) wrow = swt + ((size_t)((bm >> 12) * HEADS + bnb * 2 + wc)) * DKH;
  if (SCORE) {
#pragma unroll
    for (int m = 0; m < 4; ++m)
#pragma unroll
      for (int e = 0; e < 4; ++e) pacc[m][e] = 0.f;
  }

#pragma unroll
  for (int m = 0; m < 4; ++m)
#pragma unroll
    for (int n = 0; n < 4; ++n) {
      int c = ccol + n * 16;
      float bj = bias[c];
      float wg = SCORE ? wrow[n * 16 + l15] : 0.f;
#pragma unroll
      for (int e = 0; e < 4; ++e) {
        int r = crow + m * 16 + e;
        float v = acc[m][n][e] + bj;
        if (SCORE) pacc[m][e] += v * wg;
        if (OBF)
          ((unsigned short*)C)[(size_t)r * N + c] = f2bf(v);
        else
          ((float*)C)[(size_t)r * N + c] = v;
      }
    }

  if (SCORE) {
#pragma unroll
    for (int m = 0; m < 4; ++m)
#pragma unroll
      for (int e = 0; e < 4; ++e) {
        float p = pacc[m][e];
        p += __shfl_xor(p, 1);
        p += __shfl_xor(p, 2);
        p += __shfl_xor(p, 4);
        p += __shfl_xor(p, 8);
        if (l15 == 0) {
          int r = crow + m * 16 + e;
          int t = r & (SEQ_T - 1), n = r >> 12;
          float sc = p * 0.125f;
          if (mask[n * SEQ_T + t] == 0) sc = -3.0e38f;
          sbuf[((size_t)n * HEADS + bnb * 2 + wc) * SEQ_T + t] = sc;
        }
      }
  }
}

// ---- per-chunk softmax partials: 1024 blocks = (nh, 16 chunks of 256) ----
__global__ void __launch_bounds__(256) k_stat1(const float* __restrict__ s,
                                               float* __restrict__ pmax,
                                               float* __restrict__ psum) {
  __shared__ float red[4];
  const int b = blockIdx.x, tid = threadIdx.x, lane = tid & 63, wid = tid >> 6;
  float v = s[(size_t)b * 256 + tid];
  float m = v;
#pragma unroll
  for (int o = 1; o < 64; o <<= 1) m = fmaxf(m, __shfl_xor(m, o));
  if (lane == 0) red[wid] = m;
  __syncthreads();
  m = fmaxf(fmaxf(red[0], red[1]), fmaxf(red[2], red[3]));
  __syncthreads();
  float e = __expf(v - m);
#pragma unroll
  for (int o = 1; o < 64; o <<= 1) e += __shfl_xor(e, o);
  if (lane == 0) red[wid] = e;
  __syncthreads();
  if (tid == 0) {
    pmax[b] = m;
    psum[b] = red[0] + red[1] + red[2] + red[3];
  }
}

// ---- combine 16 chunk partials -> per-(n,h) max & 1/sum ----
__global__ void __launch_bounds__(64) k_stat2(const float* __restrict__ pmax,
                                              const float* __restrict__ psum,
                                              float* __restrict__ smx,
                                              float* __restrict__ sinv) {
  const int b = blockIdx.x, lane = threadIdx.x;
  float pm = -3.4e38f, ps = 0.f;
  if (lane < 16) {
    pm = pmax[b * 16 + lane];
    ps = psum[b * 16 + lane];
  }
  float gm = pm;
#pragma unroll
  for (int o = 1; o < 16; o <<= 1) gm = fmaxf(gm, __shfl_xor(gm, o));
  float sc = ps * __expf(pm - gm);
#pragma unroll
  for (int o = 1; o < 16; o <<= 1) sc += __shfl_xor(sc, o);
  if (lane == 0) {
    smx[b] = gm;
    sinv[b] = 1.f / sc;
  }
}

// ---- chunked weighted sum: pbuf[nh,chunk,:] = sum_t w[t]*X[n,t,h,:] (bf16 X) ----
__global__ void __launch_bounds__(256) k_wsum(const unsigned short* __restrict__ X,
                                              const float* __restrict__ s,
                                              const float* __restrict__ mxv,
                                              const float* __restrict__ invv,
                                              float* __restrict__ pbuf) {
  __shared__ float part[16][64];
  const int nh = blockIdx.x >> 4, chunk = blockIdx.x & 15;
  const int n = nh >> 4, h = nh & 15;
  const int tid = threadIdx.x, lane = tid & 63, wid = tid >> 6;
  const int tsub = lane >> 4, dl = lane & 15;
  const float mx = mxv[nh], inv = invv[nh];
  const float* sb = s + (size_t)nh * SEQ_T + chunk * 256;
  const size_t base = ((size_t)n * SEQ_T + chunk * 256) * DMODEL + h * DKH + dl * 4;
  f32x4 acc = {0.f, 0.f, 0.f, 0.f};
  for (int t = wid * 4 + tsub; t < 256; t += 16) {
    float w = __expf(sb[t] - mx) * inv;
    u16x4 xv = *(const u16x4*)(X + base + (size_t)t * DMODEL);
    acc[0] += w * bf2f(xv[0]);
    acc[1] += w * bf2f(xv[1]);
    acc[2] += w * bf2f(xv[2]);
    acc[3] += w * bf2f(xv[3]);
  }
  int g = wid * 4 + tsub;
#pragma unroll
  for (int e = 0; e < 4; ++e) part[g][dl * 4 + e] = acc[e];
  __syncthreads();
  if (tid < 64) {
    float v = 0.f;
#pragma unroll
    for (int gg = 0; gg < 16; ++gg) v += part[gg][tid];
    pbuf[(size_t)blockIdx.x * 64 + tid] = v;
  }
}

// ---- final chunk reduce. MODE 0: out=gq, wv=gq*bw. MODE 1: out=gk=v*gq ----
template <int MODE>
__global__ void __launch_bounds__(64) k_fin(const float* __restrict__ pbuf,
                                            const float* __restrict__ gq,
                                            const float* __restrict__ bw,
                                            float* __restrict__ out,
                                            float* __restrict__ wv) {
  const int nh = blockIdx.x, d = threadIdx.x;
  float v = 0.f;
#pragma unroll
  for (int c = 0; c < 16; ++c) v += pbuf[((size_t)nh * 16 + c) * 64 + d];
  if (MODE == 1) v *= gq[(size_t)nh * 64 + d];
  out[(size_t)nh * 64 + d] = v;
  if (MODE == 0) wv[(size_t)nh * 64 + d] = v * bw[d];
}

// ---- WrgT[nh][d][dd] = gk[nh][dd] * Wr[dd][d]  (bf16) ----
__global__ void __launch_bounds__(256) k_wrg(const float* __restrict__ gk,
                                             const float* __restrict__ Wr,
                                             unsigned short* __restrict__ WrgT) {
  const int nh = blockIdx.x, tid = threadIdx.x;
#pragma unroll
  for (int i = 0; i < 16; ++i) {
    int idx = i * 256 + tid;
    int d = idx >> 6, dd = idx & 63;
    WrgT[(size_t)nh * 4096 + idx] = f2bf(gk[nh * 64 + dd] * Wr[dd * 64 + d]);
  }
}

// ---- A = v @ Wrg[nh] + br + q   (MFMA, one block = 128 rows x one head) ----
#define ABM 128
#define VLD 72  // padded LDS stride
__global__ void __launch_bounds__(256) k_abuild2(const unsigned short* __restrict__ v,
                                                 const unsigned short* __restrict__ qbf,
                                                 const unsigned short* __restrict__ WrgT,
                                                 const float* __restrict__ br,
                                                 unsigned short* __restrict__ A) {
  __shared__ unsigned short Vs[ABM * VLD];
  __shared__ unsigned short Ws[DKH * VLD];
  const int tid = threadIdx.x, lane = tid & 63, wid = tid >> 6;
  const int nh = blockIdx.y;
  const int n = nh >> 4, h = nh & 15;
  const size_t nt0 = (size_t)n * SEQ_T + (size_t)blockIdx.x * ABM;
  const size_t vbase = nt0 * DMODEL + (size_t)h * DKH;
#pragma unroll
  for (int p = 0; p < 4; ++p) {
    int idx = p * 256 + tid;
    int row = idx >> 3, c = idx & 7;
    *(u32x4*)(Vs + row * VLD + c * 8) =
        *(const u32x4*)(v + vbase + (size_t)row * DMODEL + c * 8);
  }
#pragma unroll
  for (int p = 0; p < 2; ++p) {
    int idx = p * 256 + tid;
    int row = idx >> 3, c = idx & 7;
    *(u32x4*)(Ws + row * VLD + c * 8) =
        *(const u32x4*)(WrgT + (size_t)nh * 4096 + row * 64 + c * 8);
  }
  __syncthreads();
  const int l15 = lane & 15, l4 = lane >> 4;
  f32x4 acc[2][4];
#pragma unroll
  for (int m = 0; m < 2; ++m)
#pragma unroll
    for (int nf = 0; nf < 4; ++nf)
#pragma unroll
      for (int e = 0; e < 4; ++e) acc[m][nf][e] = 0.f;
#pragma unroll
  for (int ks = 0; ks < 2; ++ks) {
    bf16x8 af[2], bfr[4];
#pragma unroll
    for (int m = 0; m < 2; ++m)
      af[m] = *(const bf16x8*)(Vs + (wid * 32 + m * 16 + l15) * VLD + l4 * 8 + ks * 32);
#pragma unroll
    for (int nf = 0; nf < 4; ++nf)
      bfr[nf] = *(const bf16x8*)(Ws + (nf * 16 + l15) * VLD + l4 * 8 + ks * 32);
#pragma unroll
    for (int m = 0; m < 2; ++m)
#pragma unroll
      for (int nf = 0; nf < 4; ++nf)
        acc[m][nf] = __builtin_amdgcn_mfma_f32_16x16x32_bf16(af[m], bfr[nf],
                                                             acc[m][nf], 0, 0, 0);
  }
#pragma unroll
  for (int m = 0; m < 2; ++m)
#pragma unroll
    for (int nf = 0; nf < 4; ++nf) {
      int d = nf * 16 + l15;
      float bj = br[d];
#pragma unroll
      for (int e = 0; e < 4; ++e) {
        int r = wid * 32 + m * 16 + l4 * 4 + e;
        size_t off = vbase + (size_t)r * DMODEL + d;
        float val = acc[m][nf][e] + bj + bf2f(qbf[off]);
        A[off] = f2bf(val);
      }
    }
}

extern "C" void kernel_launch(void* const* d_in, const int* in_sizes, int n_in,
                              void* d_out, int out_size, void* d_ws, size_t ws_size,
                              hipStream_t stream) {
  const float* x_k = (const float*)d_in[0];
  const float* x_v = (const float*)d_in[1];
  const float* x_q = (const float*)d_in[2];
  const int* mask = (const int*)d_in[3];
  const float* Wk = (const float*)d_in[4];
  const float* bk = (const float*)d_in[5];
  const float* Wv = (const float*)d_in[6];
  const float* bv = (const float*)d_in[7];
  const float* Wq = (const float*)d_in[8];
  const float* bq = (const float*)d_in[9];
  const float* alpha_w = (const float*)d_in[10];
  const float* beta_w = (const float*)d_in[11];
  const float* Wr = (const float*)d_in[12];
  const float* br = (const float*)d_in[13];
  const float* Wfc = (const float*)d_in[14];
  const float* bfc = (const float*)d_in[15];

  // q (bf16) lives in d_out's first 32MB; dead before final GEMM overwrites.
  unsigned short* qbf = (unsigned short*)d_out;

  char* ws = (char*)d_ws;
  const size_t SZ_XBF = (size_t)MTOK * DMODEL * 2;  // 32 MiB
  unsigned short* kbf = (unsigned short*)(ws);
  unsigned short* vbf = (unsigned short*)(ws + SZ_XBF);
  unsigned short* xst = (unsigned short*)(ws + 2 * SZ_XBF);  // x staging, later A
  unsigned short* WkT = (unsigned short*)(ws + 3 * SZ_XBF);
  unsigned short* WvT = WkT + (size_t)DMODEL * DMODEL;
  unsigned short* WqT = WvT + (size_t)DMODEL * DMODEL;
  unsigned short* WfT = WqT + (size_t)DMODEL * DMODEL;
  unsigned short* WrgT = WfT + (size_t)DMODEL * DMODEL;     // 64*4096 bf16
  float* gq = (float*)(WrgT + (size_t)64 * 4096);
  float* gk = gq + 4096;
  float* wvb = gk + 4096;
  float* sbuf = wvb + 4096;                  // 64*4096 fp32 = 1 MiB
  float* pbuf = sbuf + (size_t)64 * SEQ_T;   // 1024*64 fp32
  float* pmax = pbuf + 1024 * 64;
  float* psum = pmax + 1024;
  float* smx = psum + 1024;
  float* sinv = smx + 64;

  dim3 tb(32, 8);
  dim3 tg(DMODEL / 32, DMODEL / 32);
  k_wtrans<<<tg, tb, 0, stream>>>(Wq, WqT, DMODEL, DMODEL);
  k_wtrans<<<tg, tb, 0, stream>>>(Wk, WkT, DMODEL, DMODEL);
  k_wtrans<<<tg, tb, 0, stream>>>(Wv, WvT, DMODEL, DMODEL);
  k_wtrans<<<tg, tb, 0, stream>>>(Wfc, WfT, DMODEL, DMODEL);

  long long nx = (long long)MTOK * DMODEL;
  int cvtg = (int)(nx / 8 / 256);
  dim3 ggrid(DMODEL / BN, MTOK / BM);

  // Q projection (+fused alpha scores), q -> bf16
  k_cvt<<<cvtg, 256, 0, stream>>>(x_q, xst, nx);
  k_gemm<1, 1><<<ggrid, 256, 0, stream>>>(xst, WqT, bq, (void*)qbf, mask, alpha_w,
                                          sbuf, MTOK, DMODEL, DMODEL);
  // alpha pooling
  k_stat1<<<1024, 256, 0, stream>>>(sbuf, pmax, psum);
  k_stat2<<<64, 64, 0, stream>>>(pmax, psum, smx, sinv);
  k_wsum<<<1024, 256, 0, stream>>>(qbf, sbuf, smx, sinv, pbuf);
  k_fin<0><<<64, 64, 0, stream>>>(pbuf, nullptr, beta_w, gq, wvb);

  // K projection (+fused beta scores)
  k_cvt<<<cvtg, 256, 0, stream>>>(x_k, xst, nx);
  k_gemm<1, 2><<<ggrid, 256, 0, stream>>>(xst, WkT, bk, (void*)kbf, mask, wvb,
                                          sbuf, MTOK, DMODEL, DMODEL);
  // beta pooling
  k_stat1<<<1024, 256, 0, stream>>>(sbuf, pmax, psum);
  k_stat2<<<64, 64, 0, stream>>>(pmax, psum, smx, sinv);
  k_wsum<<<1024, 256, 0, stream>>>(kbf, sbuf, smx, sinv, pbuf);
  k_fin<1><<<64, 64, 0, stream>>>(pbuf, gq, nullptr, gk, nullptr);

  // V projection
  k_cvt<<<cvtg, 256, 0, stream>>>(x_v, xst, nx);
  k_gemm<1, 0><<<ggrid, 256, 0, stream>>>(xst, WvT, bv, (void*)vbf, nullptr, nullptr,
                                          nullptr, MTOK, DMODEL, DMODEL);

  // A = v @ (diag(gk) Wr) + br + q
  k_wrg<<<64, 256, 0, stream>>>(gk, Wr, WrgT);
  dim3 agrid(SEQ_T / ABM, 64);
  k_abuild2<<<agrid, 256, 0, stream>>>(vbf, qbf, WrgT, br, xst);

  // final projection
  k_gemm<0, 0><<<ggrid, 256, 0, stream>>>(xst, WfT, bfc, d_out, nullptr, nullptr,
                                          nullptr, MTOK, DMODEL, DMODEL);
}

// Round 4
// 297.634 us; speedup vs baseline: 2.9503x; 1.1033x over previous
//
#include <hip/hip_runtime.h>

typedef __bf16 bf16x8 __attribute__((ext_vector_type(8)));
typedef float f32x4 __attribute__((ext_vector_type(4)));
typedef unsigned int u32x4 __attribute__((ext_vector_type(4)));
typedef unsigned short u16x4 __attribute__((ext_vector_type(4)));
typedef unsigned short u16x8 __attribute__((ext_vector_type(8)));

#define SEQ_T 4096
#define DMODEL 1024
#define HEADS 16
#define DKH 64
#define MTOK 16384  // N*T rows

#define AS1 __attribute__((address_space(1)))
#define AS3 __attribute__((address_space(3)))

__device__ __forceinline__ unsigned short f2bf(float f) {
  unsigned u = __builtin_bit_cast(unsigned int, f);
  u += 0x7FFFu + ((u >> 16) & 1u);
  return (unsigned short)(u >> 16);
}
__device__ __forceinline__ float bf2f(unsigned short h) {
  unsigned u = ((unsigned)h) << 16;
  return __builtin_bit_cast(float, u);
}
__device__ __forceinline__ void gload16(const unsigned short* g, unsigned short* l) {
  __builtin_amdgcn_global_load_lds((const AS1 unsigned int*)(g),
                                   (AS3 unsigned int*)(l), 16, 0, 0);
}

// ---------------- W (K x N) fp32 -> Wt (N x K) bf16 ----------------
__global__ void __launch_bounds__(256) k_wtrans(const float* __restrict__ W,
                                                unsigned short* __restrict__ Wt,
                                                int K, int N) {
  __shared__ float tile[32][33];
  int bn = blockIdx.x * 32, bk = blockIdx.y * 32;
  int tx = threadIdx.x, ty = threadIdx.y;  // 32 x 8
#pragma unroll
  for (int j = 0; j < 32; j += 8)
    tile[ty + j][tx] = W[(size_t)(bk + ty + j) * N + bn + tx];
  __syncthreads();
#pragma unroll
  for (int j = 0; j < 32; j += 8)
    Wt[(size_t)(bn + ty + j) * K + bk + tx] = f2bf(tile[tx][ty + j]);
}

// ===================== 256x256 bf16 NT GEMM, BK=64, 8 waves =================
// C = A(MxK) * Bt(NxK)^T + bias.  AF32: A is fp32 (converted while staging).
// SCORE=1: fused alpha scores (swt[64]); SCORE=2: beta scores (swt[nh][64]).
// T2 XOR swizzle (chunk ^= row&7) via pre-swizzled global source, swizzled
// ds_read.  Double-buffered LDS, staged loads stay in flight across the end
// barrier (raw s_barrier; drained by near-free vmcnt(0) next iteration).
#define BM 256
#define BN 256
#define BK 64

template <int OBF, int SCORE, int AF32>
__global__ void __launch_bounds__(512, 2)
k_gemm(const void* __restrict__ Ain, const unsigned short* __restrict__ Bt,
       const float* __restrict__ bias, void* __restrict__ C,
       const int* __restrict__ mask, const float* __restrict__ swt,
       float* __restrict__ sbuf, int M, int N, int K) {
  __shared__ unsigned short Asb[2][BM * BK];
  __shared__ unsigned short Bsb[2][BN * BK];
  const int tid = threadIdx.x;
  const int lane = tid & 63, wid = tid >> 6;
  const int wr = wid >> 2, wc = wid & 3;  // 2 x 4 wave grid; wave out: 128x64
  const int l15 = lane & 15, l4 = lane >> 4;

  // bijective XCD swizzle (nwg=256, %8==0): chunk per XCD
  const int nwg = gridDim.x * gridDim.y;
  const int flat = blockIdx.x + blockIdx.y * gridDim.x;
  const int rm = (flat & 7) * (nwg >> 3) + (flat >> 3);
  const int bx = rm % gridDim.x, by = rm / gridDim.x;
  const int bm = by * BM, bn = bx * BN;

  const float* Af = (const float*)Ain;
  const unsigned short* Abf = (const unsigned short*)Ain;

  f32x4 acc[8][4];
#pragma unroll
  for (int i = 0; i < 8; ++i)
#pragma unroll
    for (int j = 0; j < 4; ++j)
#pragma unroll
      for (int e = 0; e < 4; ++e) acc[i][j][e] = 0.f;

  // ---- staging geometry ----
  // gload_lds: wave instr j covers 8 rows (group g = wid*4+j); lane l ->
  // row g*8 + (l>>3), source chunk (l&7)^(l>>3); LDS linear (swizzled slot).
  const int sgr = lane >> 3;            // 0..7
  const int sgc = (lane & 7) ^ sgr;     // pre-swizzled source chunk
  // fp32 A reg-staging: thread slot s: row r0+s*64, lds chunk c7l, src c7s
  const int r0 = tid >> 3;              // 0..63
  const int c7l = tid & 7;
  const int c7s = c7l ^ (r0 & 7);

  f32x4 alo[4], ahi[4];
  auto loadA32 = [&](int t) {
#pragma unroll
    for (int s = 0; s < 4; ++s) {
      const float* src = Af + (size_t)(bm + r0 + s * 64) * K + t * BK + c7s * 8;
      alo[s] = *(const f32x4*)src;
      ahi[s] = *(const f32x4*)(src + 4);
    }
  };
  auto writeA32 = [&](int t) {
    unsigned short* dst = &Asb[t & 1][0];
#pragma unroll
    for (int s = 0; s < 4; ++s) {
      u16x8 o;
#pragma unroll
      for (int j = 0; j < 4; ++j) {
        o[j] = f2bf(alo[s][j]);
        o[4 + j] = f2bf(ahi[s][j]);
      }
      *(u16x8*)(dst + (r0 + s * 64) * BK + c7l * 8) = o;
    }
  };
  auto stageAbf = [&](int t) {
    unsigned short* dst = &Asb[t & 1][0];
#pragma unroll
    for (int j = 0; j < 4; ++j) {
      int g = wid * 4 + j;
      gload16(Abf + (size_t)(bm + g * 8 + sgr) * K + t * BK + sgc * 8,
              dst + g * 512);
    }
  };
  auto stageB = [&](int t) {
    unsigned short* dst = &Bsb[t & 1][0];
#pragma unroll
    for (int j = 0; j < 4; ++j) {
      int g = wid * 4 + j;
      gload16(Bt + (size_t)(bn + g * 8 + sgr) * K + t * BK + sgc * 8,
              dst + g * 512);
    }
  };

  const int nt = K / BK;
  // prologue: tile 0
  if (AF32) {
    loadA32(0);
    writeA32(0);
  } else {
    stageAbf(0);
  }
  stageB(0);

  for (int t = 0; t < nt; ++t) {
    asm volatile("s_waitcnt vmcnt(0)" ::: "memory");
    asm volatile("s_waitcnt lgkmcnt(0)" ::: "memory");
    __builtin_amdgcn_s_barrier();
    const bool pf = (t + 1 < nt);
    if (pf) {
      if (AF32) loadA32(t + 1); else stageAbf(t + 1);
      stageB(t + 1);
    }
    const unsigned short* Ab = &Asb[t & 1][0];
    const unsigned short* Bb = &Bsb[t & 1][0];
#pragma unroll
    for (int ks = 0; ks < 2; ++ks) {
      bf16x8 bfr[4];
#pragma unroll
      for (int nf = 0; nf < 4; ++nf) {
        int rowb = wc * 64 + nf * 16 + l15;
        int c7 = (ks * 4 + l4) ^ (rowb & 7);
        bfr[nf] = *(const bf16x8*)(Bb + rowb * BK + c7 * 8);
      }
#pragma unroll
      for (int mh = 0; mh < 2; ++mh) {
        bf16x8 af[4];
#pragma unroll
        for (int i = 0; i < 4; ++i) {
          int rowa = wr * 128 + (mh * 4 + i) * 16 + l15;
          int c7 = (ks * 4 + l4) ^ (rowa & 7);
          af[i] = *(const bf16x8*)(Ab + rowa * BK + c7 * 8);
        }
        __builtin_amdgcn_s_setprio(1);
#pragma unroll
        for (int i = 0; i < 4; ++i)
#pragma unroll
          for (int nf = 0; nf < 4; ++nf)
            acc[mh * 4 + i][nf] = __builtin_amdgcn_mfma_f32_16x16x32_bf16(
                af[i], bfr[nf], acc[mh * 4 + i][nf], 0, 0, 0);
        __builtin_amdgcn_s_setprio(0);
      }
    }
    if (pf && AF32) writeA32(t + 1);
    asm volatile("s_waitcnt lgkmcnt(0)" ::: "memory");
    __builtin_amdgcn_s_barrier();
  }

  // ---- epilogue: bias, C write, optional fused scores ----
  const int crow = bm + wr * 128 + l4 * 4;
  const int ccol = bn + wc * 64 + l15;
  float pacc[8][4];
  const float* wrow = nullptr;
  if (SCORE == 1) wrow = swt;
  if (SCORE == 2)
    wrow = swt + ((size_t)((bm >> 12) * HEADS + bx * 4 + wc)) * DKH;
  if (SCORE) {
#pragma unroll
    for (int m = 0; m < 8; ++m)
#pragma unroll
      for (int e = 0; e < 4; ++e) pacc[m][e] = 0.f;
  }

#pragma unroll
  for (int m = 0; m < 8; ++m)
#pragma unroll
    for (int nf = 0; nf < 4; ++nf) {
      int c = ccol + nf * 16;
      float bj = bias[c];
      float wg = SCORE ? wrow[nf * 16 + l15] : 0.f;
#pragma unroll
      for (int e = 0; e < 4; ++e) {
        int r = crow + m * 16 + e;
        float v = acc[m][nf][e] + bj;
        if (SCORE) pacc[m][e] += v * wg;
        if (OBF)
          ((unsigned short*)C)[(size_t)r * N + c] = f2bf(v);
        else
          ((float*)C)[(size_t)r * N + c] = v;
      }
    }

  if (SCORE) {
#pragma unroll
    for (int m = 0; m < 8; ++m)
#pragma unroll
      for (int e = 0; e < 4; ++e) {
        float p = pacc[m][e];
        p += __shfl_xor(p, 1);
        p += __shfl_xor(p, 2);
        p += __shfl_xor(p, 4);
        p += __shfl_xor(p, 8);
        if (l15 == 0) {
          int r = crow + m * 16 + e;
          int t = r & (SEQ_T - 1), n = r >> 12;
          float sc = p * 0.125f;
          if (mask[n * SEQ_T + t] == 0) sc = -3.0e38f;
          sbuf[((size_t)n * HEADS + bx * 4 + wc) * SEQ_T + t] = sc;
        }
      }
  }
}

// ---- per-chunk softmax partials: 1024 blocks = (nh, 16 chunks of 256) ----
__global__ void __launch_bounds__(256) k_stat1(const float* __restrict__ s,
                                               float* __restrict__ pmax,
                                               float* __restrict__ psum) {
  __shared__ float red[4];
  const int b = blockIdx.x, tid = threadIdx.x, lane = tid & 63, wid = tid >> 6;
  float v = s[(size_t)b * 256 + tid];
  float m = v;
#pragma unroll
  for (int o = 1; o < 64; o <<= 1) m = fmaxf(m, __shfl_xor(m, o));
  if (lane == 0) red[wid] = m;
  __syncthreads();
  m = fmaxf(fmaxf(red[0], red[1]), fmaxf(red[2], red[3]));
  __syncthreads();
  float e = __expf(v - m);
#pragma unroll
  for (int o = 1; o < 64; o <<= 1) e += __shfl_xor(e, o);
  if (lane == 0) red[wid] = e;
  __syncthreads();
  if (tid == 0) {
    pmax[b] = m;
    psum[b] = red[0] + red[1] + red[2] + red[3];
  }
}

// ---- combine 16 chunk partials -> per-(n,h) max & 1/sum ----
__global__ void __launch_bounds__(64) k_stat2(const float* __restrict__ pmax,
                                              const float* __restrict__ psum,
                                              float* __restrict__ smx,
                                              float* __restrict__ sinv) {
  const int b = blockIdx.x, lane = threadIdx.x;
  float pm = -3.4e38f, ps = 0.f;
  if (lane < 16) {
    pm = pmax[b * 16 + lane];
    ps = psum[b * 16 + lane];
  }
  float gm = pm;
#pragma unroll
  for (int o = 1; o < 16; o <<= 1) gm = fmaxf(gm, __shfl_xor(gm, o));
  float sc = ps * __expf(pm - gm);
#pragma unroll
  for (int o = 1; o < 16; o <<= 1) sc += __shfl_xor(sc, o);
  if (lane == 0) {
    smx[b] = gm;
    sinv[b] = 1.f / sc;
  }
}

// ---- chunked weighted sum: pbuf[nh,chunk,:] = sum_t w[t]*X[n,t,h,:] (bf16 X) ----
__global__ void __launch_bounds__(256) k_wsum(const unsigned short* __restrict__ X,
                                              const float* __restrict__ s,
                                              const float* __restrict__ mxv,
                                              const float* __restrict__ invv,
                                              float* __restrict__ pbuf) {
  __shared__ float part[16][64];
  const int nh = blockIdx.x >> 4, chunk = blockIdx.x & 15;
  const int n = nh >> 4, h = nh & 15;
  const int tid = threadIdx.x, lane = tid & 63, wid = tid >> 6;
  const int tsub = lane >> 4, dl = lane & 15;
  const float mx = mxv[nh], inv = invv[nh];
  const float* sb = s + (size_t)nh * SEQ_T + chunk * 256;
  const size_t base = ((size_t)n * SEQ_T + chunk * 256) * DMODEL + h * DKH + dl * 4;
  f32x4 acc = {0.f, 0.f, 0.f, 0.f};
  for (int t = wid * 4 + tsub; t < 256; t += 16) {
    float w = __expf(sb[t] - mx) * inv;
    u16x4 xv = *(const u16x4*)(X + base + (size_t)t * DMODEL);
    acc[0] += w * bf2f(xv[0]);
    acc[1] += w * bf2f(xv[1]);
    acc[2] += w * bf2f(xv[2]);
    acc[3] += w * bf2f(xv[3]);
  }
  int g = wid * 4 + tsub;
#pragma unroll
  for (int e = 0; e < 4; ++e) part[g][dl * 4 + e] = acc[e];
  __syncthreads();
  if (tid < 64) {
    float v = 0.f;
#pragma unroll
    for (int gg = 0; gg < 16; ++gg) v += part[gg][tid];
    pbuf[(size_t)blockIdx.x * 64 + tid] = v;
  }
}

// ---- final chunk reduce. MODE 0: out=gq, wv=gq*bw. MODE 1: out=gk=v*gq ----
template <int MODE>
__global__ void __launch_bounds__(64) k_fin(const float* __restrict__ pbuf,
                                            const float* __restrict__ gq,
                                            const float* __restrict__ bw,
                                            float* __restrict__ out,
                                            float* __restrict__ wv) {
  const int nh = blockIdx.x, d = threadIdx.x;
  float v = 0.f;
#pragma unroll
  for (int c = 0; c < 16; ++c) v += pbuf[((size_t)nh * 16 + c) * 64 + d];
  if (MODE == 1) v *= gq[(size_t)nh * 64 + d];
  out[(size_t)nh * 64 + d] = v;
  if (MODE == 0) wv[(size_t)nh * 64 + d] = v * bw[d];
}

// ---- WrgT[nh][d][dd] = gk[nh][dd] * Wr[dd][d]  (bf16) ----
__global__ void __launch_bounds__(256) k_wrg(const float* __restrict__ gk,
                                             const float* __restrict__ Wr,
                                             unsigned short* __restrict__ WrgT) {
  const int nh = blockIdx.x, tid = threadIdx.x;
#pragma unroll
  for (int i = 0; i < 16; ++i) {
    int idx = i * 256 + tid;
    int d = idx >> 6, dd = idx & 63;
    WrgT[(size_t)nh * 4096 + idx] = f2bf(gk[nh * 64 + dd] * Wr[dd * 64 + d]);
  }
}

// ---- A = v @ Wrg[nh] + br + q   (MFMA, one block = 128 rows x one head) ----
#define ABM 128
#define VLD 72  // padded LDS stride
__global__ void __launch_bounds__(256) k_abuild2(const unsigned short* __restrict__ v,
                                                 const unsigned short* __restrict__ qbf,
                                                 const unsigned short* __restrict__ WrgT,
                                                 const float* __restrict__ br,
                                                 unsigned short* __restrict__ A) {
  __shared__ unsigned short Vs[ABM * VLD];
  __shared__ unsigned short Ws[DKH * VLD];
  const int tid = threadIdx.x, lane = tid & 63, wid = tid >> 6;
  const int nh = blockIdx.y;
  const int n = nh >> 4, h = nh & 15;
  const size_t nt0 = (size_t)n * SEQ_T + (size_t)blockIdx.x * ABM;
  const size_t vbase = nt0 * DMODEL + (size_t)h * DKH;
#pragma unroll
  for (int p = 0; p < 4; ++p) {
    int idx = p * 256 + tid;
    int row = idx >> 3, c = idx & 7;
    *(u32x4*)(Vs + row * VLD + c * 8) =
        *(const u32x4*)(v + vbase + (size_t)row * DMODEL + c * 8);
  }
#pragma unroll
  for (int p = 0; p < 2; ++p) {
    int idx = p * 256 + tid;
    int row = idx >> 3, c = idx & 7;
    *(u32x4*)(Ws + row * VLD + c * 8) =
        *(const u32x4*)(WrgT + (size_t)nh * 4096 + row * 64 + c * 8);
  }
  __syncthreads();
  const int l15 = lane & 15, l4 = lane >> 4;
  f32x4 acc[2][4];
#pragma unroll
  for (int m = 0; m < 2; ++m)
#pragma unroll
    for (int nf = 0; nf < 4; ++nf)
#pragma unroll
      for (int e = 0; e < 4; ++e) acc[m][nf][e] = 0.f;
#pragma unroll
  for (int ks = 0; ks < 2; ++ks) {
    bf16x8 af[2], bfr[4];
#pragma unroll
    for (int m = 0; m < 2; ++m)
      af[m] = *(const bf16x8*)(Vs + (wid * 32 + m * 16 + l15) * VLD + l4 * 8 + ks * 32);
#pragma unroll
    for (int nf = 0; nf < 4; ++nf)
      bfr[nf] = *(const bf16x8*)(Ws + (nf * 16 + l15) * VLD + l4 * 8 + ks * 32);
#pragma unroll
    for (int m = 0; m < 2; ++m)
#pragma unroll
      for (int nf = 0; nf < 4; ++nf)
        acc[m][nf] = __builtin_amdgcn_mfma_f32_16x16x32_bf16(af[m], bfr[nf],
                                                             acc[m][nf], 0, 0, 0);
  }
#pragma unroll
  for (int m = 0; m < 2; ++m)
#pragma unroll
    for (int nf = 0; nf < 4; ++nf) {
      int d = nf * 16 + l15;
      float bj = br[d];
#pragma unroll
      for (int e = 0; e < 4; ++e) {
        int r = wid * 32 + m * 16 + l4 * 4 + e;
        size_t off = vbase + (size_t)r * DMODEL + d;
        float val = acc[m][nf][e] + bj + bf2f(qbf[off]);
        A[off] = f2bf(val);
      }
    }
}

extern "C" void kernel_launch(void* const* d_in, const int* in_sizes, int n_in,
                              void* d_out, int out_size, void* d_ws, size_t ws_size,
                              hipStream_t stream) {
  const float* x_k = (const float*)d_in[0];
  const float* x_v = (const float*)d_in[1];
  const float* x_q = (const float*)d_in[2];
  const int* mask = (const int*)d_in[3];
  const float* Wk = (const float*)d_in[4];
  const float* bk = (const float*)d_in[5];
  const float* Wv = (const float*)d_in[6];
  const float* bv = (const float*)d_in[7];
  const float* Wq = (const float*)d_in[8];
  const float* bq = (const float*)d_in[9];
  const float* alpha_w = (const float*)d_in[10];
  const float* beta_w = (const float*)d_in[11];
  const float* Wr = (const float*)d_in[12];
  const float* br = (const float*)d_in[13];
  const float* Wfc = (const float*)d_in[14];
  const float* bfc = (const float*)d_in[15];

  // q (bf16) lives in d_out's first 32MB; dead before final GEMM overwrites.
  unsigned short* qbf = (unsigned short*)d_out;

  char* ws = (char*)d_ws;
  const size_t SZ_XBF = (size_t)MTOK * DMODEL * 2;  // 32 MiB
  unsigned short* kbf = (unsigned short*)(ws);
  unsigned short* vbf = (unsigned short*)(ws + SZ_XBF);
  unsigned short* xst = (unsigned short*)(ws + 2 * SZ_XBF);  // A matrix
  unsigned short* WkT = (unsigned short*)(ws + 3 * SZ_XBF);
  unsigned short* WvT = WkT + (size_t)DMODEL * DMODEL;
  unsigned short* WqT = WvT + (size_t)DMODEL * DMODEL;
  unsigned short* WfT = WqT + (size_t)DMODEL * DMODEL;
  unsigned short* WrgT = WfT + (size_t)DMODEL * DMODEL;     // 64*4096 bf16
  float* gq = (float*)(WrgT + (size_t)64 * 4096);
  float* gk = gq + 4096;
  float* wvb = gk + 4096;
  float* sbuf = wvb + 4096;                  // 64*4096 fp32 = 1 MiB
  float* pbuf = sbuf + (size_t)64 * SEQ_T;   // 1024*64 fp32
  float* pmax = pbuf + 1024 * 64;
  float* psum = pmax + 1024;
  float* smx = psum + 1024;
  float* sinv = smx + 64;

  dim3 tb(32, 8);
  dim3 tg(DMODEL / 32, DMODEL / 32);
  k_wtrans<<<tg, tb, 0, stream>>>(Wq, WqT, DMODEL, DMODEL);
  k_wtrans<<<tg, tb, 0, stream>>>(Wk, WkT, DMODEL, DMODEL);
  k_wtrans<<<tg, tb, 0, stream>>>(Wv, WvT, DMODEL, DMODEL);
  k_wtrans<<<tg, tb, 0, stream>>>(Wfc, WfT, DMODEL, DMODEL);

  dim3 ggrid(DMODEL / BN, MTOK / BM);  // (4, 64)

  // Q projection (fp32 A, fused alpha scores), q -> bf16
  k_gemm<1, 1, 1><<<ggrid, 512, 0, stream>>>(x_q, WqT, bq, (void*)qbf, mask,
                                             alpha_w, sbuf, MTOK, DMODEL, DMODEL);
  // alpha pooling
  k_stat1<<<1024, 256, 0, stream>>>(sbuf, pmax, psum);
  k_stat2<<<64, 64, 0, stream>>>(pmax, psum, smx, sinv);
  k_wsum<<<1024, 256, 0, stream>>>(qbf, sbuf, smx, sinv, pbuf);
  k_fin<0><<<64, 64, 0, stream>>>(pbuf, nullptr, beta_w, gq, wvb);

  // K projection (fp32 A, fused beta scores)
  k_gemm<1, 2, 1><<<ggrid, 512, 0, stream>>>(x_k, WkT, bk, (void*)kbf, mask,
                                             wvb, sbuf, MTOK, DMODEL, DMODEL);
  // beta pooling
  k_stat1<<<1024, 256, 0, stream>>>(sbuf, pmax, psum);
  k_stat2<<<64, 64, 0, stream>>>(pmax, psum, smx, sinv);
  k_wsum<<<1024, 256, 0, stream>>>(kbf, sbuf, smx, sinv, pbuf);
  k_fin<1><<<64, 64, 0, stream>>>(pbuf, gq, nullptr, gk, nullptr);

  // V projection (fp32 A)
  k_gemm<1, 0, 1><<<ggrid, 512, 0, stream>>>(x_v, WvT, bv, (void*)vbf, nullptr,
                                             nullptr, nullptr, MTOK, DMODEL, DMODEL);

  // A = v @ (diag(gk) Wr) + br + q
  k_wrg<<<64, 256, 0, stream>>>(gk, Wr, WrgT);
  dim3 agrid(SEQ_T / ABM, 64);
  k_abuild2<<<agrid, 256, 0, stream>>>(vbf, qbf, WrgT, br, xst);

  // final projection (bf16 A)
  k_gemm<0, 0, 0><<<ggrid, 512, 0, stream>>>(xst, WfT, bfc, d_out, nullptr,
                                             nullptr, nullptr, MTOK, DMODEL, DMODEL);
}

// Round 5
// 296.319 us; speedup vs baseline: 2.9634x; 1.0044x over previous
//
#include <hip/hip_runtime.h>

typedef __bf16 bf16x8 __attribute__((ext_vector_type(8)));
typedef float f32x4 __attribute__((ext_vector_type(4)));
typedef unsigned int u32x4 __attribute__((ext_vector_type(4)));
typedef unsigned short u16x4 __attribute__((ext_vector_type(4)));
typedef unsigned short u16x8 __attribute__((ext_vector_type(8)));

#define SEQ_T 4096
#define DMODEL 1024
#define HEADS 16
#define DKH 64
#define MTOK 16384  // N*T rows

#define AS1 __attribute__((address_space(1)))
#define AS3 __attribute__((address_space(3)))
#define MEMFENCE asm volatile("" ::: "memory")

__device__ __forceinline__ unsigned short f2bf(float f) {
  unsigned u = __builtin_bit_cast(unsigned int, f);
  u += 0x7FFFu + ((u >> 16) & 1u);
  return (unsigned short)(u >> 16);
}
__device__ __forceinline__ float bf2f(unsigned short h) {
  unsigned u = ((unsigned)h) << 16;
  return __builtin_bit_cast(float, u);
}
__device__ __forceinline__ void gload16(const unsigned short* g, unsigned short* l) {
  __builtin_amdgcn_global_load_lds((const AS1 unsigned int*)(g),
                                   (AS3 unsigned int*)(l), 16, 0, 0);
}

// ---------------- W (K x N) fp32 -> Wt (N x K) bf16 ----------------
__global__ void __launch_bounds__(256) k_wtrans(const float* __restrict__ W,
                                                unsigned short* __restrict__ Wt,
                                                int K, int N) {
  __shared__ float tile[32][33];
  int bn = blockIdx.x * 32, bk = blockIdx.y * 32;
  int tx = threadIdx.x, ty = threadIdx.y;  // 32 x 8
#pragma unroll
  for (int j = 0; j < 32; j += 8)
    tile[ty + j][tx] = W[(size_t)(bk + ty + j) * N + bn + tx];
  __syncthreads();
#pragma unroll
  for (int j = 0; j < 32; j += 8)
    Wt[(size_t)(bn + ty + j) * K + bk + tx] = f2bf(tile[tx][ty + j]);
}

// ============ 256x256 bf16 NT GEMM, BK=64, 8 waves (8Mx1N), 4-phase ==========
// C = A(MxK)*Bt(NxK)^T + bias.  AF32: A fp32, converted in reg-staging.
// Per K-tile: 4 phases (one 64-col block x K=64, 16 MFMA each).
// Staging duty rota (per phase, counted-vmcnt ledger):
//   p0: A(t+1) half0 (or AF32 reg-load of full A(t+1))
//   p1: A(t+1) half1 (gload path only)        -> wait vmcnt(4|8) end of p1
//   p2: B(t+2) half0
//   p3: B(t+1) half1 (+ AF32 cvt/ds_write)    -> wait vmcnt(4) end of p3
// Every half is >=3 phases old at the wait that requires it; waits never
// drain the newest in-flight halves (T3+T4).  setprio around MFMA (T5).
#define BM 256
#define BN 256
#define BK 64

template <int OBF, int SCORE, int AF32>
__global__ void __launch_bounds__(512, 2)
k_gemm(const void* __restrict__ Ain, const unsigned short* __restrict__ Bt,
       const float* __restrict__ bias, void* __restrict__ C,
       const int* __restrict__ mask, const float* __restrict__ swt,
       float* __restrict__ sbuf, int M, int N, int K) {
  __shared__ unsigned short As[2][2][128 * 64];  // [parity][half][row*64+col]
  __shared__ unsigned short Bs[2][2][128 * 64];
  const int tid = threadIdx.x;
  const int lane = tid & 63, wid = tid >> 6;
  const int l15 = lane & 15, l4 = lane >> 4;

  // bijective XCD swizzle (nwg=256, %8==0)
  const int nwg = gridDim.x * gridDim.y;
  const int flat = blockIdx.x + blockIdx.y * gridDim.x;
  const int rm = (flat & 7) * (nwg >> 3) + (flat >> 3);
  const int bx = rm % gridDim.x, by = rm / gridDim.x;
  const int bm = by * BM, bn = bx * BN;

  const float* Af = (const float*)Ain;
  const unsigned short* Abf = (const unsigned short*)Ain;
  const int nt = K / BK;

  f32x4 acc[2][16];
#pragma unroll
  for (int m = 0; m < 2; ++m)
#pragma unroll
    for (int nf = 0; nf < 16; ++nf)
#pragma unroll
      for (int e = 0; e < 4; ++e) acc[m][nf][e] = 0.f;

  // gload_lds staging: 1 half (128 rows x 64) = 2 instrs/wave; lane l ->
  // row group g*8 + (l>>3), src chunk (l&7)^(l>>3) (pre-swizzled), LDS linear.
  const int sgr = lane >> 3;
  const int sgc = (lane & 7) ^ sgr;
  // AF32 reg staging: thread -> rows r0+s*64, linear src col c8*8 (f32),
  // swizzled ds_write chunk cw (conflict-free: cw varies across 8-row group).
  const int r0 = tid >> 3;
  const int c8 = tid & 7;
  const int cw = c8 ^ (r0 & 7);
  f32x4 alo[4], ahi[4];

  auto stageA = [&](int t, int h) {
#pragma unroll
    for (int j = 0; j < 2; ++j) {
      int g = wid * 2 + j;
      gload16(Abf + (size_t)(bm + h * 128 + g * 8 + sgr) * K + t * BK + sgc * 8,
              &As[t & 1][h][g * 512]);
    }
  };
  auto stageB = [&](int t, int h) {
#pragma unroll
    for (int j = 0; j < 2; ++j) {
      int g = wid * 2 + j;
      gload16(Bt + (size_t)(bn + h * 128 + g * 8 + sgr) * K + t * BK + sgc * 8,
              &Bs[t & 1][h][g * 512]);
    }
  };
  auto aload = [&](int t) {  // 8 vm events
#pragma unroll
    for (int s = 0; s < 4; ++s) {
      const float* src = Af + (size_t)(bm + r0 + s * 64) * K + t * BK + c8 * 8;
      alo[s] = *(const f32x4*)src;
      ahi[s] = *(const f32x4*)(src + 4);
    }
  };
  auto awrite = [&](int t) {
#pragma unroll
    for (int s = 0; s < 4; ++s) {
      int row = r0 + s * 64;
      u16x8 o;
#pragma unroll
      for (int j = 0; j < 4; ++j) {
        o[j] = f2bf(alo[s][j]);
        o[4 + j] = f2bf(ahi[s][j]);
      }
      *(u16x8*)(&As[t & 1][row >> 7][(row & 127) * 64 + cw * 8]) = o;
    }
  };

  // ---- prologue: tile0 resident; B0(1) in flight ----
  if (AF32) {
    aload(0);
    stageB(0, 0);
    stageB(0, 1);
    stageB(1, 0);
    awrite(0);  // compiler waits vmcnt(6) for alo/ahi
    asm volatile("s_waitcnt lgkmcnt(0)" ::: "memory");
    asm volatile("s_waitcnt vmcnt(4)" ::: "memory");
  } else {
    stageA(0, 0);
    stageA(0, 1);
    stageB(0, 0);
    stageB(0, 1);
    stageB(1, 0);
    asm volatile("s_waitcnt vmcnt(4)" ::: "memory");
  }
  __builtin_amdgcn_s_barrier();
  MEMFENCE;

  bf16x8 afr[2][2];
  for (int t = 0; t < nt; ++t) {
    const int cur = t & 1;
#pragma unroll
    for (int p = 0; p < 4; ++p) {
      // ---- register subtile loads (current tile) ----
      if (p == 0) {
#pragma unroll
        for (int m = 0; m < 2; ++m)
#pragma unroll
          for (int ks = 0; ks < 2; ++ks) {
            int rh = (wid & 3) * 32 + m * 16 + l15;
            int c7 = (ks * 4 + l4) ^ (rh & 7);
            afr[m][ks] = *(const bf16x8*)(&As[cur][wid >> 2][rh * 64 + c7 * 8]);
          }
      }
      bf16x8 bfr[4][2];
#pragma unroll
      for (int nf = 0; nf < 4; ++nf)
#pragma unroll
        for (int ks = 0; ks < 2; ++ks) {
          int rh = (p & 1) * 64 + nf * 16 + l15;
          int c7 = (ks * 4 + l4) ^ (rh & 7);
          bfr[nf][ks] = *(const bf16x8*)(&Bs[cur][p >> 1][rh * 64 + c7 * 8]);
        }
      // ---- staging duties ----
      if (p == 0) {
        if (t + 1 < nt) {
          if (AF32) aload(t + 1);
          else stageA(t + 1, 0);
        }
      } else if (p == 1) {
        if (!AF32 && t + 1 < nt) stageA(t + 1, 1);
      } else if (p == 2) {
        if (t + 2 < nt) stageB(t + 2, 0);
      } else {
        if (t + 1 < nt) {
          stageB(t + 1, 1);
          if (AF32) awrite(t + 1);
        }
      }
      // ---- counted waits (never drain newest halves) ----
      if (p == 1) {
        if (AF32) asm volatile("s_waitcnt vmcnt(8)" ::: "memory");
        else asm volatile("s_waitcnt vmcnt(4)" ::: "memory");
      } else if (p == 3) {
        if (AF32) asm volatile("s_waitcnt lgkmcnt(0)" ::: "memory");
        asm volatile("s_waitcnt vmcnt(4)" ::: "memory");
      }
      MEMFENCE;
      __builtin_amdgcn_s_barrier();
      MEMFENCE;
      __builtin_amdgcn_s_setprio(1);
#pragma unroll
      for (int m = 0; m < 2; ++m)
#pragma unroll
        for (int nf = 0; nf < 4; ++nf)
#pragma unroll
          for (int ks = 0; ks < 2; ++ks)
            acc[m][p * 4 + nf] = __builtin_amdgcn_mfma_f32_16x16x32_bf16(
                afr[m][ks], bfr[nf][ks], acc[m][p * 4 + nf], 0, 0, 0);
      __builtin_amdgcn_s_setprio(0);
      MEMFENCE;
      __builtin_amdgcn_s_barrier();
      MEMFENCE;
    }
  }

  // ---- epilogue: bias, C write, optional fused scores ----
  const int crow = bm + wid * 32 + l4 * 4;
  float pacc[2][4][4];
  if (SCORE) {
#pragma unroll
    for (int m = 0; m < 2; ++m)
#pragma unroll
      for (int hh = 0; hh < 4; ++hh)
#pragma unroll
        for (int e = 0; e < 4; ++e) pacc[m][hh][e] = 0.f;
  }

#pragma unroll
  for (int m = 0; m < 2; ++m)
#pragma unroll
    for (int nf = 0; nf < 16; ++nf) {
      int c = bn + nf * 16 + l15;
      float bj = bias[c];
      float wg = 0.f;
      if (SCORE == 1) wg = swt[(nf & 3) * 16 + l15];
      if (SCORE == 2)
        wg = swt[((size_t)((bm >> 12) * HEADS + bx * 4 + (nf >> 2))) * DKH +
                 (nf & 3) * 16 + l15];
#pragma unroll
      for (int e = 0; e < 4; ++e) {
        int r = crow + m * 16 + e;
        float v = acc[m][nf][e] + bj;
        if (SCORE) pacc[m][nf >> 2][e] += v * wg;
        if (OBF)
          ((unsigned short*)C)[(size_t)r * N + c] = f2bf(v);
        else
          ((float*)C)[(size_t)r * N + c] = v;
      }
    }

  if (SCORE) {
#pragma unroll
    for (int m = 0; m < 2; ++m)
#pragma unroll
      for (int hh = 0; hh < 4; ++hh)
#pragma unroll
        for (int e = 0; e < 4; ++e) {
          float pv = pacc[m][hh][e];
          pv += __shfl_xor(pv, 1);
          pv += __shfl_xor(pv, 2);
          pv += __shfl_xor(pv, 4);
          pv += __shfl_xor(pv, 8);
          if (l15 == 0) {
            int r = crow + m * 16 + e;
            int tt = r & (SEQ_T - 1), n = r >> 12;
            float sc = pv * 0.125f;
            if (mask[n * SEQ_T + tt] == 0) sc = -3.0e38f;
            sbuf[((size_t)n * HEADS + bx * 4 + hh) * SEQ_T + tt] = sc;
          }
        }
  }
}

// ---- per-chunk softmax partials: 1024 blocks = (nh, 16 chunks of 256) ----
__global__ void __launch_bounds__(256) k_stat1(const float* __restrict__ s,
                                               float* __restrict__ pmax,
                                               float* __restrict__ psum) {
  __shared__ float red[4];
  const int b = blockIdx.x, tid = threadIdx.x, lane = tid & 63, wid = tid >> 6;
  float v = s[(size_t)b * 256 + tid];
  float m = v;
#pragma unroll
  for (int o = 1; o < 64; o <<= 1) m = fmaxf(m, __shfl_xor(m, o));
  if (lane == 0) red[wid] = m;
  __syncthreads();
  m = fmaxf(fmaxf(red[0], red[1]), fmaxf(red[2], red[3]));
  __syncthreads();
  float e = __expf(v - m);
#pragma unroll
  for (int o = 1; o < 64; o <<= 1) e += __shfl_xor(e, o);
  if (lane == 0) red[wid] = e;
  __syncthreads();
  if (tid == 0) {
    pmax[b] = m;
    psum[b] = red[0] + red[1] + red[2] + red[3];
  }
}

// ---- combine 16 chunk partials -> per-(n,h) max & 1/sum ----
__global__ void __launch_bounds__(64) k_stat2(const float* __restrict__ pmax,
                                              const float* __restrict__ psum,
                                              float* __restrict__ smx,
                                              float* __restrict__ sinv) {
  const int b = blockIdx.x, lane = threadIdx.x;
  float pm = -3.4e38f, ps = 0.f;
  if (lane < 16) {
    pm = pmax[b * 16 + lane];
    ps = psum[b * 16 + lane];
  }
  float gm = pm;
#pragma unroll
  for (int o = 1; o < 16; o <<= 1) gm = fmaxf(gm, __shfl_xor(gm, o));
  float sc = ps * __expf(pm - gm);
#pragma unroll
  for (int o = 1; o < 16; o <<= 1) sc += __shfl_xor(sc, o);
  if (lane == 0) {
    smx[b] = gm;
    sinv[b] = 1.f / sc;
  }
}

// ---- chunked weighted sum: pbuf[nh,chunk,:] = sum_t w[t]*X[n,t,h,:] (bf16 X) ----
__global__ void __launch_bounds__(256) k_wsum(const unsigned short* __restrict__ X,
                                              const float* __restrict__ s,
                                              const float* __restrict__ mxv,
                                              const float* __restrict__ invv,
                                              float* __restrict__ pbuf) {
  __shared__ float part[16][64];
  const int nh = blockIdx.x >> 4, chunk = blockIdx.x & 15;
  const int n = nh >> 4, h = nh & 15;
  const int tid = threadIdx.x, lane = tid & 63, wid = tid >> 6;
  const int tsub = lane >> 4, dl = lane & 15;
  const float mx = mxv[nh], inv = invv[nh];
  const float* sb = s + (size_t)nh * SEQ_T + chunk * 256;
  const size_t base = ((size_t)n * SEQ_T + chunk * 256) * DMODEL + h * DKH + dl * 4;
  f32x4 acc = {0.f, 0.f, 0.f, 0.f};
  for (int t = wid * 4 + tsub; t < 256; t += 16) {
    float w = __expf(sb[t] - mx) * inv;
    u16x4 xv = *(const u16x4*)(X + base + (size_t)t * DMODEL);
    acc[0] += w * bf2f(xv[0]);
    acc[1] += w * bf2f(xv[1]);
    acc[2] += w * bf2f(xv[2]);
    acc[3] += w * bf2f(xv[3]);
  }
  int g = wid * 4 + tsub;
#pragma unroll
  for (int e = 0; e < 4; ++e) part[g][dl * 4 + e] = acc[e];
  __syncthreads();
  if (tid < 64) {
    float v = 0.f;
#pragma unroll
    for (int gg = 0; gg < 16; ++gg) v += part[gg][tid];
    pbuf[(size_t)blockIdx.x * 64 + tid] = v;
  }
}

// ---- final chunk reduce. MODE 0: out=gq, wv=gq*bw. MODE 1: out=gk=v*gq ----
template <int MODE>
__global__ void __launch_bounds__(64) k_fin(const float* __restrict__ pbuf,
                                            const float* __restrict__ gq,
                                            const float* __restrict__ bw,
                                            float* __restrict__ out,
                                            float* __restrict__ wv) {
  const int nh = blockIdx.x, d = threadIdx.x;
  float v = 0.f;
#pragma unroll
  for (int c = 0; c < 16; ++c) v += pbuf[((size_t)nh * 16 + c) * 64 + d];
  if (MODE == 1) v *= gq[(size_t)nh * 64 + d];
  out[(size_t)nh * 64 + d] = v;
  if (MODE == 0) wv[(size_t)nh * 64 + d] = v * bw[d];
}

// ---- WrgT[nh][d][dd] = gk[nh][dd] * Wr[dd][d]  (bf16) ----
__global__ void __launch_bounds__(256) k_wrg(const float* __restrict__ gk,
                                             const float* __restrict__ Wr,
                                             unsigned short* __restrict__ WrgT) {
  const int nh = blockIdx.x, tid = threadIdx.x;
#pragma unroll
  for (int i = 0; i < 16; ++i) {
    int idx = i * 256 + tid;
    int d = idx >> 6, dd = idx & 63;
    WrgT[(size_t)nh * 4096 + idx] = f2bf(gk[nh * 64 + dd] * Wr[dd * 64 + d]);
  }
}

// ---- A = v @ Wrg[nh] + br + q   (MFMA, one block = 128 rows x one head) ----
#define ABM 128
#define VLD 72  // padded LDS stride
__global__ void __launch_bounds__(256) k_abuild2(const unsigned short* __restrict__ v,
                                                 const unsigned short* __restrict__ qbf,
                                                 const unsigned short* __restrict__ WrgT,
                                                 const float* __restrict__ br,
                                                 unsigned short* __restrict__ A) {
  __shared__ unsigned short Vs[ABM * VLD];
  __shared__ unsigned short Ws[DKH * VLD];
  const int tid = threadIdx.x, lane = tid & 63, wid = tid >> 6;
  const int nh = blockIdx.y;
  const int n = nh >> 4, h = nh & 15;
  const size_t nt0 = (size_t)n * SEQ_T + (size_t)blockIdx.x * ABM;
  const size_t vbase = nt0 * DMODEL + (size_t)h * DKH;
#pragma unroll
  for (int p = 0; p < 4; ++p) {
    int idx = p * 256 + tid;
    int row = idx >> 3, c = idx & 7;
    *(u32x4*)(Vs + row * VLD + c * 8) =
        *(const u32x4*)(v + vbase + (size_t)row * DMODEL + c * 8);
  }
#pragma unroll
  for (int p = 0; p < 2; ++p) {
    int idx = p * 256 + tid;
    int row = idx >> 3, c = idx & 7;
    *(u32x4*)(Ws + row * VLD + c * 8) =
        *(const u32x4*)(WrgT + (size_t)nh * 4096 + row * 64 + c * 8);
  }
  __syncthreads();
  const int l15 = lane & 15, l4 = lane >> 4;
  f32x4 acc[2][4];
#pragma unroll
  for (int m = 0; m < 2; ++m)
#pragma unroll
    for (int nf = 0; nf < 4; ++nf)
#pragma unroll
      for (int e = 0; e < 4; ++e) acc[m][nf][e] = 0.f;
#pragma unroll
  for (int ks = 0; ks < 2; ++ks) {
    bf16x8 af[2], bfr[4];
#pragma unroll
    for (int m = 0; m < 2; ++m)
      af[m] = *(const bf16x8*)(Vs + (wid * 32 + m * 16 + l15) * VLD + l4 * 8 + ks * 32);
#pragma unroll
    for (int nf = 0; nf < 4; ++nf)
      bfr[nf] = *(const bf16x8*)(Ws + (nf * 16 + l15) * VLD + l4 * 8 + ks * 32);
#pragma unroll
    for (int m = 0; m < 2; ++m)
#pragma unroll
      for (int nf = 0; nf < 4; ++nf)
        acc[m][nf] = __builtin_amdgcn_mfma_f32_16x16x32_bf16(af[m], bfr[nf],
                                                             acc[m][nf], 0, 0, 0);
  }
#pragma unroll
  for (int m = 0; m < 2; ++m)
#pragma unroll
    for (int nf = 0; nf < 4; ++nf) {
      int d = nf * 16 + l15;
      float bj = br[d];
#pragma unroll
      for (int e = 0; e < 4; ++e) {
        int r = wid * 32 + m * 16 + l4 * 4 + e;
        size_t off = vbase + (size_t)r * DMODEL + d;
        float val = acc[m][nf][e] + bj + bf2f(qbf[off]);
        A[off] = f2bf(val);
      }
    }
}

extern "C" void kernel_launch(void* const* d_in, const int* in_sizes, int n_in,
                              void* d_out, int out_size, void* d_ws, size_t ws_size,
                              hipStream_t stream) {
  const float* x_k = (const float*)d_in[0];
  const float* x_v = (const float*)d_in[1];
  const float* x_q = (const float*)d_in[2];
  const int* mask = (const int*)d_in[3];
  const float* Wk = (const float*)d_in[4];
  const float* bk = (const float*)d_in[5];
  const float* Wv = (const float*)d_in[6];
  const float* bv = (const float*)d_in[7];
  const float* Wq = (const float*)d_in[8];
  const float* bq = (const float*)d_in[9];
  const float* alpha_w = (const float*)d_in[10];
  const float* beta_w = (const float*)d_in[11];
  const float* Wr = (const float*)d_in[12];
  const float* br = (const float*)d_in[13];
  const float* Wfc = (const float*)d_in[14];
  const float* bfc = (const float*)d_in[15];

  // q (bf16) lives in d_out's first 32MB; dead before final GEMM overwrites.
  unsigned short* qbf = (unsigned short*)d_out;

  char* ws = (char*)d_ws;
  const size_t SZ_XBF = (size_t)MTOK * DMODEL * 2;  // 32 MiB
  unsigned short* kbf = (unsigned short*)(ws);
  unsigned short* vbf = (unsigned short*)(ws + SZ_XBF);
  unsigned short* xst = (unsigned short*)(ws + 2 * SZ_XBF);  // A matrix
  unsigned short* WkT = (unsigned short*)(ws + 3 * SZ_XBF);
  unsigned short* WvT = WkT + (size_t)DMODEL * DMODEL;
  unsigned short* WqT = WvT + (size_t)DMODEL * DMODEL;
  unsigned short* WfT = WqT + (size_t)DMODEL * DMODEL;
  unsigned short* WrgT = WfT + (size_t)DMODEL * DMODEL;     // 64*4096 bf16
  float* gq = (float*)(WrgT + (size_t)64 * 4096);
  float* gk = gq + 4096;
  float* wvb = gk + 4096;
  float* sbuf = wvb + 4096;                  // 64*4096 fp32 = 1 MiB
  float* pbuf = sbuf + (size_t)64 * SEQ_T;   // 1024*64 fp32
  float* pmax = pbuf + 1024 * 64;
  float* psum = pmax + 1024;
  float* smx = psum + 1024;
  float* sinv = smx + 64;

  dim3 tb(32, 8);
  dim3 tg(DMODEL / 32, DMODEL / 32);
  k_wtrans<<<tg, tb, 0, stream>>>(Wq, WqT, DMODEL, DMODEL);
  k_wtrans<<<tg, tb, 0, stream>>>(Wk, WkT, DMODEL, DMODEL);
  k_wtrans<<<tg, tb, 0, stream>>>(Wv, WvT, DMODEL, DMODEL);
  k_wtrans<<<tg, tb, 0, stream>>>(Wfc, WfT, DMODEL, DMODEL);

  dim3 ggrid(DMODEL / BN, MTOK / BM);  // (4, 64)

  // Q projection (fp32 A, fused alpha scores), q -> bf16
  k_gemm<1, 1, 1><<<ggrid, 512, 0, stream>>>(x_q, WqT, bq, (void*)qbf, mask,
                                             alpha_w, sbuf, MTOK, DMODEL, DMODEL);
  // alpha pooling
  k_stat1<<<1024, 256, 0, stream>>>(sbuf, pmax, psum);
  k_stat2<<<64, 64, 0, stream>>>(pmax, psum, smx, sinv);
  k_wsum<<<1024, 256, 0, stream>>>(qbf, sbuf, smx, sinv, pbuf);
  k_fin<0><<<64, 64, 0, stream>>>(pbuf, nullptr, beta_w, gq, wvb);

  // K projection (fp32 A, fused beta scores)
  k_gemm<1, 2, 1><<<ggrid, 512, 0, stream>>>(x_k, WkT, bk, (void*)kbf, mask,
                                             wvb, sbuf, MTOK, DMODEL, DMODEL);
  // beta pooling
  k_stat1<<<1024, 256, 0, stream>>>(sbuf, pmax, psum);
  k_stat2<<<64, 64, 0, stream>>>(pmax, psum, smx, sinv);
  k_wsum<<<1024, 256, 0, stream>>>(kbf, sbuf, smx, sinv, pbuf);
  k_fin<1><<<64, 64, 0, stream>>>(pbuf, gq, nullptr, gk, nullptr);

  // V projection (fp32 A)
  k_gemm<1, 0, 1><<<ggrid, 512, 0, stream>>>(x_v, WvT, bv, (void*)vbf, nullptr,
                                             nullptr, nullptr, MTOK, DMODEL, DMODEL);

  // A = v @ (diag(gk) Wr) + br + q
  k_wrg<<<64, 256, 0, stream>>>(gk, Wr, WrgT);
  dim3 agrid(SEQ_T / ABM, 64);
  k_abuild2<<<agrid, 256, 0, stream>>>(vbf, qbf, WrgT, br, xst);

  // final projection (bf16 A)
  k_gemm<0, 0, 0><<<ggrid, 512, 0, stream>>>(xst, WfT, bfc, d_out, nullptr,
                                             nullptr, nullptr, MTOK, DMODEL, DMODEL);
}